// Round 12
// baseline (395.558 us; speedup 1.0000x reference)
//
#include <hip/hip_runtime.h>
#include <stdint.h>

typedef unsigned short ushort_t;
typedef __attribute__((ext_vector_type(8))) short short8;
typedef __attribute__((ext_vector_type(8))) _Float16 half8;
typedef __attribute__((ext_vector_type(4))) float f32x4;
typedef __attribute__((ext_vector_type(4))) unsigned short us4;

#define AS1 __attribute__((address_space(1)))
#define AS3 __attribute__((address_space(3)))

#if __has_builtin(__builtin_amdgcn_exp2f)
#define EXP2(x) __builtin_amdgcn_exp2f(x)
#else
#define EXP2(x) exp2f(x)
#endif

// scores are multiplied by 8 (the reference's /scale bug); fold into exp2 base
#define SC 11.541560327111707f  // 8 * log2(e)

__device__ __forceinline__ ushort_t f2h(float f) {
  _Float16 h = (_Float16)f;   // v_cvt_f16_f32, RNE
  return __builtin_bit_cast(unsigned short, h);
}

__device__ __forceinline__ void gload16(const void* g, void* l) {
  __builtin_amdgcn_global_load_lds((AS1 const void*)g, (AS3 void*)l, 16, 0, 0);
}

__device__ __forceinline__ f32x4 mfma16(short8 a, short8 b, f32x4 c) {
  return __builtin_amdgcn_mfma_f32_16x16x32_f16(
      __builtin_bit_cast(half8, a), __builtin_bit_cast(half8, b), c, 0, 0, 0);
}

// ---------------- cast x fp32 -> fp16 ----------------
__global__ __launch_bounds__(256) void cast_f32_f16(const float4* __restrict__ in,
                                                    us4* __restrict__ out, int n4) {
  int i = blockIdx.x * 256 + threadIdx.x;
  int stride = gridDim.x * 256;
  for (; i < n4; i += stride) {
    float4 v = in[i];
    us4 o;
    o[0] = f2h(v.x); o[1] = f2h(v.y); o[2] = f2h(v.z); o[3] = f2h(v.w);
    out[i] = o;
  }
}

// ---------------- transpose-cast W [R][C] fp32 -> Wt [C][R] fp16 ----------------
__global__ __launch_bounds__(256) void tcast(const float* __restrict__ in,
                                             ushort_t* __restrict__ out, int R, int C) {
  __shared__ __align__(16) float lt[32][33];
  const int r0 = blockIdx.y * 32, c0 = blockIdx.x * 32;
  const int i = threadIdx.x;
  const int lr = i >> 3, lc = (i & 7) * 4;
  float4 v = *(const float4*)(in + (size_t)(r0 + lr) * C + c0 + lc);
  lt[lr][lc + 0] = v.x; lt[lr][lc + 1] = v.y; lt[lr][lc + 2] = v.z; lt[lr][lc + 3] = v.w;
  __syncthreads();
  const int oc = i >> 3;          // out row (a column c of in)
  const int orr = (i & 7) * 4;    // out col (row r of in)
  us4 o;
#pragma unroll
  for (int jj = 0; jj < 4; ++jj) o[jj] = f2h(lt[orr + jj][oc]);
  *(us4*)(out + (size_t)(c0 + oc) * R + r0 + orr) = o;
}

// ---------------- 128x128 fp16 GEMM, BK=64, A[M][K] x Bt[N][K] ----------------
// MODE 0: epilogue scatters Q,K into [bh][t][d] (fp16) and V TRANSPOSED into [bh][d][t]
// MODE 1: epilogue writes fp32 out[M][N]
template<int MODE>
__global__ __launch_bounds__(256) void gemm128(
    const ushort_t* __restrict__ A, const ushort_t* __restrict__ Bt, int K, int N,
    ushort_t* __restrict__ qo, ushort_t* __restrict__ ko, ushort_t* __restrict__ vo,
    float* __restrict__ outp)
{
  __shared__ __align__(16) unsigned char lds[32768];   // A tile 16K, B tile 16K
  const int tid = threadIdx.x;
  const int lane = tid & 63, w = tid >> 6;
  const int ln = lane & 15, gq = lane >> 4;
  const int wr = w >> 1, wc = w & 1;
  const int m0 = blockIdx.y * 128, n0 = blockIdx.x * 128;
  const size_t ldb = (size_t)K * 2;  // row bytes
  const unsigned char* ab = (const unsigned char*)A + (size_t)m0 * ldb;
  const unsigned char* bb = (const unsigned char*)Bt + (size_t)n0 * ldb;
  f32x4 acc[4][4] = {};
  const int nkt = K >> 6;
  for (int kb = 0; kb < nkt; ++kb) {
    const unsigned char* abk = ab + kb * 128;
    const unsigned char* bbk = bb + kb * 128;
#pragma unroll
    for (int e = 0; e < 4; ++e) {
      unsigned o = e * 4096 + tid * 16;
      unsigned r = o >> 7;
      unsigned c = (o & 127) ^ ((r & 7) << 4);   // pre-swizzled source
      gload16(abk + (size_t)r * ldb + c, lds + o);
      gload16(bbk + (size_t)r * ldb + c, lds + 16384 + o);
    }
    __syncthreads();
    short8 af[4][2], bf8[4][2];
#pragma unroll
    for (int mi = 0; mi < 4; ++mi) {
      unsigned row = wr * 64 + mi * 16 + ln;
      unsigned c0 = (gq * 16) ^ ((row & 7) << 4);
      af[mi][0] = *(const short8*)(lds + row * 128 + c0);
      af[mi][1] = *(const short8*)(lds + row * 128 + (c0 ^ 64));
    }
#pragma unroll
    for (int ni = 0; ni < 4; ++ni) {
      unsigned row = wc * 64 + ni * 16 + ln;
      unsigned c0 = (gq * 16) ^ ((row & 7) << 4);
      bf8[ni][0] = *(const short8*)(lds + 16384 + row * 128 + c0);
      bf8[ni][1] = *(const short8*)(lds + 16384 + row * 128 + (c0 ^ 64));
    }
#pragma unroll
    for (int mi = 0; mi < 4; ++mi)
#pragma unroll
      for (int ni = 0; ni < 4; ++ni) {
        acc[mi][ni] = mfma16(af[mi][0], bf8[ni][0], acc[mi][ni]);
        acc[mi][ni] = mfma16(af[mi][1], bf8[ni][1], acc[mi][ni]);
      }
    __syncthreads();
  }
  // epilogue: D layout col = lane&15, row = (lane>>4)*4 + j
  if (MODE == 0) {
#pragma unroll
    for (int mi = 0; mi < 4; ++mi)
#pragma unroll
      for (int ni = 0; ni < 4; ++ni) {
        int feat = n0 + wc * 64 + ni * 16 + ln;
        int sec = feat >> 10, cc = feat & 1023;   // sec is wave-uniform per (wc,ni)
        int hh = cc >> 6, dd = cc & 63;
        int tokbase = m0 + wr * 64 + mi * 16 + gq * 4;   // j=0 token (multiple of 4)
        int bh = (tokbase >> 11) * 16 + hh;
        int tloc = tokbase & 2047;
        if (sec == 2) {
          // V transposed: [bh][d][t], 4 consecutive tokens -> one 8B store
          us4 pk;
#pragma unroll
          for (int j = 0; j < 4; ++j) pk[j] = f2h(acc[mi][ni][j]);
          *(us4*)(vo + ((size_t)bh * 64 + dd) * 2048 + tloc) = pk;
        } else {
          ushort_t* dst = (sec == 0) ? qo : ko;
#pragma unroll
          for (int j = 0; j < 4; ++j) {
            size_t off = ((size_t)bh * 2048 + tloc + j) * 64 + dd;
            dst[off] = f2h(acc[mi][ni][j]);
          }
        }
      }
  } else {
#pragma unroll
    for (int mi = 0; mi < 4; ++mi)
#pragma unroll
      for (int ni = 0; ni < 4; ++ni)
#pragma unroll
        for (int j = 0; j < 4; ++j) {
          int token = m0 + wr * 64 + mi * 16 + gq * 4 + j;
          int feat  = n0 + wc * 64 + ni * 16 + ln;
          outp[(size_t)token * N + feat] = acc[mi][ni][j];
        }
  }
}

// ---------------- flash attention: causal pair-balanced, QBLK=64, KVBLK=64 ----------------
// BARRIER-FREE, ALL-DIRECT: K and Vt fragments load straight from global (L2-hot,
// XCD-grouped); no K/V LDS staging, no __syncthreads. LDS holds only the per-wave
// P buffer (8KB/block). Swapped QK^T (softmax lane-local), deferred rescale,
// fma-folded exp2, setprio around MFMA clusters.
__global__ __launch_bounds__(256) void attn_kernel(const ushort_t* __restrict__ qg,
                                                   const ushort_t* __restrict__ kg,
                                                   const ushort_t* __restrict__ vtg,
                                                   ushort_t* __restrict__ yg) {
  __shared__ __align__(16) unsigned char lds[8192];   // P per-wave @ w*2048
  const int n = blockIdx.x;                 // 0..1023
  const int xcd = n & 7, loc = n >> 3;      // XCD-grouped decode
  const int bh = xcd * 8 + (loc >> 4);      // 0..63; all 16 pair-blocks of a bh on one XCD
  const int pair = loc & 15;                // 0..15
  const int tid = threadIdx.x;
  const int lane = tid & 63, w = tid >> 6;
  const int ln = lane & 15, gq = lane >> 4;

  const ushort_t* kg_bh = kg + (size_t)bh * 2048 * 64;   // [2048 t][64 d]
  const ushort_t* vt_bh = vtg + (size_t)bh * 64 * 2048;  // [64 d][2048 t]
  const ushort_t* qg_bh = qg + (size_t)bh * 2048 * 64;
  const unsigned pw = w * 2048;

  for (int ph = 0; ph < 2; ++ph) {
    const int qt = (ph == 0) ? pair : 31 - pair;
    const int q0 = qt * 64;
    const int nt = qt + 1;

    // Q fragments: lane ln holds q-row (w*16+ln), k = st*32 + gq*8 + j
    const ushort_t* qrow = qg_bh + (size_t)(q0 + w * 16 + ln) * 64;
    short8 qa0 = *(const short8*)(qrow + gq * 8);
    short8 qa1 = *(const short8*)(qrow + 32 + gq * 8);

    f32x4 yacc[4] = {};
    float mrow = -3e38f, lrow = 0.f;   // lane-local state for q-row = w*16+ln

    for (int t = 0; t < nt; ++t) {
      // K fragments direct from global: K[kv = f*16+ln][d = gq*8..+8 (+32)]
      const ushort_t* kt_g = kg_bh + (size_t)t * 64 * 64;
      short8 kf0[4], kf1[4];
#pragma unroll
      for (int f = 0; f < 4; ++f) {
        const ushort_t* kr = kt_g + (unsigned)(f * 16 + ln) * 64 + gq * 8;
        kf0[f] = *(const short8*)kr;
        kf1[f] = *(const short8*)(kr + 32);
      }
      // swapped QK^T: S^T[kv][q]; col=ln=q, row=gq*4+j (+f*16 = kv)
      f32x4 s[4];
      __builtin_amdgcn_s_setprio(1);
#pragma unroll
      for (int f = 0; f < 4; ++f) {
        f32x4 z = {0.f, 0.f, 0.f, 0.f};
        z = mfma16(kf0[f], qa0, z);
        s[f] = mfma16(kf1[f], qa1, z);
      }
      __builtin_amdgcn_s_setprio(0);
      if (t == nt - 1) {   // diagonal tile (kv0 == q0): mask kv > q in local coords
        int qloc = w * 16 + ln;
#pragma unroll
        for (int f = 0; f < 4; ++f) {
          int kvb = f * 16 + gq * 4;
#pragma unroll
          for (int j = 0; j < 4; ++j)
            if (kvb + j > qloc) s[f][j] = -3e38f;
        }
      }
      // online softmax: lane holds 16 scores all for q = w*16+ln
      // deferred rescale (THR=8 exp2-units) + fma-folded exp2
      {
        float rm = s[0][0];
#pragma unroll
        for (int f = 0; f < 4; ++f)
#pragma unroll
          for (int j = 0; j < 4; ++j) rm = fmaxf(rm, s[f][j]);
        rm = fmaxf(rm, __shfl_xor(rm, 16));
        rm = fmaxf(rm, __shfl_xor(rm, 32));
        if (__any((rm - mrow) * SC > 8.0f)) {
          float mnew = fmaxf(mrow, rm);
          float alpha = EXP2((mrow - mnew) * SC);
          lrow *= alpha;
          mrow = mnew;
#pragma unroll
          for (int j = 0; j < 4; ++j) {
            float aj = __shfl(alpha, gq * 4 + j);   // alpha of q-row gq*4+j
#pragma unroll
            for (int df = 0; df < 4; ++df) yacc[df][j] *= aj;
          }
        }
        float msc = mrow * SC;
        float rs = 0.f;
#pragma unroll
        for (int f = 0; f < 4; ++f)
#pragma unroll
          for (int j = 0; j < 4; ++j) {
            float p = EXP2(__builtin_fmaf(s[f][j], SC, -msc));
            s[f][j] = p;
            rs += p;
          }
        rs += __shfl_xor(rs, 16);
        rs += __shfl_xor(rs, 32);
        lrow += rs;
      }
      // write P -> per-wave LDS as P[16 q][64 kv]: lane owns row q=ln,
      // cols kv=f*16+gq*4..+3 (within-wave ds ordering via lgkmcnt, no barrier)
#pragma unroll
      for (int f = 0; f < 4; ++f) {
        us4 pk;
#pragma unroll
        for (int j = 0; j < 4; ++j) pk[j] = f2h(s[f][j]);
        unsigned addr = (pw + ln * 128 + (f * 16 + gq * 4) * 2) ^ ((ln & 7) << 4);
        *(us4*)(lds + addr) = pk;
      }
      // PV: y[16 q][64 d] += P[16 q][64 kv] * V[64 kv][64 d]
      // V fragments direct from global: Vt[d = df*16+ln][kv = t*64 + st*32 + gq*8..+8]
      const ushort_t* vt_t = vt_bh + t * 64;
      __builtin_amdgcn_s_setprio(1);
#pragma unroll
      for (int st = 0; st < 2; ++st) {
        unsigned pc = (st * 64 + gq * 16) ^ ((ln & 7) << 4);
        short8 pa = *(const short8*)(lds + pw + ln * 128 + pc);
#pragma unroll
        for (int df = 0; df < 4; ++df) {
          const ushort_t* vr = vt_t + (size_t)(df * 16 + ln) * 2048 + st * 32 + gq * 8;
          short8 vb = *(const short8*)vr;
          yacc[df] = mfma16(pa, vb, yacc[df]);
        }
      }
      __builtin_amdgcn_s_setprio(0);
    }

    // epilogue for this phase: y[b][t][h*64+d] fp16 (lrow lives at lane q; broadcast)
#pragma unroll
    for (int j = 0; j < 4; ++j) {
      float lj = __shfl(lrow, gq * 4 + j);
      float rl = 1.0f / lj;
      int tq = q0 + w * 16 + gq * 4 + j;
#pragma unroll
      for (int df = 0; df < 4; ++df) {
        int col = (bh & 15) * 64 + df * 16 + ln;
        size_t off = ((size_t)(bh >> 4) * 2048 + tq) * 1024 + col;
        yg[off] = f2h(yacc[df][j] * rl);
      }
    }
  }
}

extern "C" void kernel_launch(void* const* d_in, const int* in_sizes, int n_in,
                              void* d_out, int out_size, void* d_ws, size_t ws_size,
                              hipStream_t stream) {
  (void)in_sizes; (void)n_in; (void)out_size; (void)ws_size;
  const float* x     = (const float*)d_in[0];
  const float* wqkv  = (const float*)d_in[1];
  const float* wproj = (const float*)d_in[2];
  float* out = (float*)d_out;
  char* ws = (char*)d_ws;
  // ws layout (bytes)
  ushort_t* xb   = (ushort_t*)(ws);               // 16MB  (reused as y after QKV GEMM)
  ushort_t* wqkt = (ushort_t*)(ws + 16777216);    // 6MB
  ushort_t* wpt  = (ushort_t*)(ws + 23068672);    // 2MB
  ushort_t* qb_  = (ushort_t*)(ws + 25165824);    // 16MB [bh][t][d]
  ushort_t* kb_  = (ushort_t*)(ws + 41943040);    // 16MB [bh][t][d]
  ushort_t* vt   = (ushort_t*)(ws + 75497472);    // 16MB [bh][d][t] (written by gemm<0>)
  ushort_t* yb   = xb;

  cast_f32_f16<<<2048, 256, 0, stream>>>((const float4*)x, (us4*)xb, 2097152);
  tcast<<<dim3(96, 32), 256, 0, stream>>>(wqkv, wqkt, 1024, 3072);
  tcast<<<dim3(32, 32), 256, 0, stream>>>(wproj, wpt, 1024, 1024);
  gemm128<0><<<dim3(24, 64), 256, 0, stream>>>(xb, wqkt, 1024, 3072, qb_, kb_, vt, nullptr);
  attn_kernel<<<1024, 256, 0, stream>>>(qb_, kb_, vt, yb);
  gemm128<1><<<dim3(8, 64), 256, 0, stream>>>(yb, wpt, 1024, 1024, nullptr, nullptr, nullptr, out);
}

// Round 13
// 274.713 us; speedup vs baseline: 1.4399x; 1.4399x over previous
//
#include <hip/hip_runtime.h>
#include <stdint.h>

typedef unsigned short ushort_t;
typedef __attribute__((ext_vector_type(8))) short short8;
typedef __attribute__((ext_vector_type(8))) _Float16 half8;
typedef __attribute__((ext_vector_type(4))) float f32x4;
typedef __attribute__((ext_vector_type(4))) unsigned short us4;

#define AS1 __attribute__((address_space(1)))
#define AS3 __attribute__((address_space(3)))

#if __has_builtin(__builtin_amdgcn_exp2f)
#define EXP2(x) __builtin_amdgcn_exp2f(x)
#else
#define EXP2(x) exp2f(x)
#endif

// scores are multiplied by 8 (the reference's /scale bug); fold into exp2 base
#define SC 11.541560327111707f  // 8 * log2(e)

__device__ __forceinline__ ushort_t f2h(float f) {
  _Float16 h = (_Float16)f;   // v_cvt_f16_f32, RNE
  return __builtin_bit_cast(unsigned short, h);
}

__device__ __forceinline__ void gload16(const void* g, void* l) {
  __builtin_amdgcn_global_load_lds((AS1 const void*)g, (AS3 void*)l, 16, 0, 0);
}

__device__ __forceinline__ f32x4 mfma16(short8 a, short8 b, f32x4 c) {
  return __builtin_amdgcn_mfma_f32_16x16x32_f16(
      __builtin_bit_cast(half8, a), __builtin_bit_cast(half8, b), c, 0, 0, 0);
}

// ---------------- cast x fp32 -> fp16 ----------------
__global__ __launch_bounds__(256) void cast_f32_f16(const float4* __restrict__ in,
                                                    us4* __restrict__ out, int n4) {
  int i = blockIdx.x * 256 + threadIdx.x;
  int stride = gridDim.x * 256;
  for (; i < n4; i += stride) {
    float4 v = in[i];
    us4 o;
    o[0] = f2h(v.x); o[1] = f2h(v.y); o[2] = f2h(v.z); o[3] = f2h(v.w);
    out[i] = o;
  }
}

// ---------------- transpose-cast W [R][C] fp32 -> Wt [C][R] fp16 ----------------
__global__ __launch_bounds__(256) void tcast(const float* __restrict__ in,
                                             ushort_t* __restrict__ out, int R, int C) {
  __shared__ __align__(16) float lt[32][33];
  const int r0 = blockIdx.y * 32, c0 = blockIdx.x * 32;
  const int i = threadIdx.x;
  const int lr = i >> 3, lc = (i & 7) * 4;
  float4 v = *(const float4*)(in + (size_t)(r0 + lr) * C + c0 + lc);
  lt[lr][lc + 0] = v.x; lt[lr][lc + 1] = v.y; lt[lr][lc + 2] = v.z; lt[lr][lc + 3] = v.w;
  __syncthreads();
  const int oc = i >> 3;          // out row (a column c of in)
  const int orr = (i & 7) * 4;    // out col (row r of in)
  us4 o;
#pragma unroll
  for (int jj = 0; jj < 4; ++jj) o[jj] = f2h(lt[orr + jj][oc]);
  *(us4*)(out + (size_t)(c0 + oc) * R + r0 + orr) = o;
}

// ---------------- 128x128 fp16 GEMM, BK=64, A[M][K] x Bt[N][K] ----------------
// MODE 0: epilogue scatters Q,K into [bh][t][d] (fp16) and V TRANSPOSED into [bh][d][t]
// MODE 1: epilogue writes fp32 out[M][N]
template<int MODE>
__global__ __launch_bounds__(256) void gemm128(
    const ushort_t* __restrict__ A, const ushort_t* __restrict__ Bt, int K, int N,
    ushort_t* __restrict__ qo, ushort_t* __restrict__ ko, ushort_t* __restrict__ vo,
    float* __restrict__ outp)
{
  __shared__ __align__(16) unsigned char lds[32768];   // A tile 16K, B tile 16K
  const int tid = threadIdx.x;
  const int lane = tid & 63, w = tid >> 6;
  const int ln = lane & 15, gq = lane >> 4;
  const int wr = w >> 1, wc = w & 1;
  const int m0 = blockIdx.y * 128, n0 = blockIdx.x * 128;
  const size_t ldb = (size_t)K * 2;  // row bytes
  const unsigned char* ab = (const unsigned char*)A + (size_t)m0 * ldb;
  const unsigned char* bb = (const unsigned char*)Bt + (size_t)n0 * ldb;
  f32x4 acc[4][4] = {};
  const int nkt = K >> 6;
  for (int kb = 0; kb < nkt; ++kb) {
    const unsigned char* abk = ab + kb * 128;
    const unsigned char* bbk = bb + kb * 128;
#pragma unroll
    for (int e = 0; e < 4; ++e) {
      unsigned o = e * 4096 + tid * 16;
      unsigned r = o >> 7;
      unsigned c = (o & 127) ^ ((r & 7) << 4);   // pre-swizzled source
      gload16(abk + (size_t)r * ldb + c, lds + o);
      gload16(bbk + (size_t)r * ldb + c, lds + 16384 + o);
    }
    __syncthreads();
    short8 af[4][2], bf8[4][2];
#pragma unroll
    for (int mi = 0; mi < 4; ++mi) {
      unsigned row = wr * 64 + mi * 16 + ln;
      unsigned c0 = (gq * 16) ^ ((row & 7) << 4);
      af[mi][0] = *(const short8*)(lds + row * 128 + c0);
      af[mi][1] = *(const short8*)(lds + row * 128 + (c0 ^ 64));
    }
#pragma unroll
    for (int ni = 0; ni < 4; ++ni) {
      unsigned row = wc * 64 + ni * 16 + ln;
      unsigned c0 = (gq * 16) ^ ((row & 7) << 4);
      bf8[ni][0] = *(const short8*)(lds + 16384 + row * 128 + c0);
      bf8[ni][1] = *(const short8*)(lds + 16384 + row * 128 + (c0 ^ 64));
    }
#pragma unroll
    for (int mi = 0; mi < 4; ++mi)
#pragma unroll
      for (int ni = 0; ni < 4; ++ni) {
        acc[mi][ni] = mfma16(af[mi][0], bf8[ni][0], acc[mi][ni]);
        acc[mi][ni] = mfma16(af[mi][1], bf8[ni][1], acc[mi][ni]);
      }
    __syncthreads();
  }
  // epilogue: D layout col = lane&15, row = (lane>>4)*4 + j
  if (MODE == 0) {
#pragma unroll
    for (int mi = 0; mi < 4; ++mi)
#pragma unroll
      for (int ni = 0; ni < 4; ++ni) {
        int feat = n0 + wc * 64 + ni * 16 + ln;
        int sec = feat >> 10, cc = feat & 1023;   // sec is wave-uniform per (wc,ni)
        int hh = cc >> 6, dd = cc & 63;
        int tokbase = m0 + wr * 64 + mi * 16 + gq * 4;   // j=0 token (multiple of 4)
        int bh = (tokbase >> 11) * 16 + hh;
        int tloc = tokbase & 2047;
        if (sec == 2) {
          // V transposed: [bh][d][t], 4 consecutive tokens -> one 8B store
          us4 pk;
#pragma unroll
          for (int j = 0; j < 4; ++j) pk[j] = f2h(acc[mi][ni][j]);
          *(us4*)(vo + ((size_t)bh * 64 + dd) * 2048 + tloc) = pk;
        } else {
          ushort_t* dst = (sec == 0) ? qo : ko;
#pragma unroll
          for (int j = 0; j < 4; ++j) {
            size_t off = ((size_t)bh * 2048 + tloc + j) * 64 + dd;
            dst[off] = f2h(acc[mi][ni][j]);
          }
        }
      }
  } else {
#pragma unroll
    for (int mi = 0; mi < 4; ++mi)
#pragma unroll
      for (int ni = 0; ni < 4; ++ni)
#pragma unroll
        for (int j = 0; j < 4; ++j) {
          int token = m0 + wr * 64 + mi * 16 + gq * 4 + j;
          int feat  = n0 + wc * 64 + ni * 16 + ln;
          outp[(size_t)token * N + feat] = acc[mi][ni][j];
        }
  }
}

// ---------------- flash attention: QBLK=64, KVBLK=32, 8 blocks/CU ----------------
// High-TLP operating point: staged dbuf + depth-1 prefetch + 1 barrier/tile (r11
// structure), but footprint shrunk so 8 blocks fit per CU (LDS 20480B, VGPR<=64 via
// launch_bounds). Grid 2048 (1 q-tile/block); CU-local long/short interleave makes
// any 8 consecutive blocks sum to equal work. Swapped QK^T softmax (lane-local),
// deferred rescale, fma-folded exp2, setprio on MFMA clusters.
// LDS: K dbuf @0/4096 (32x128B swizzled), V dbuf @8192/12288 (64x64B linear),
//      P per-wave @16384 + w*1024 (16q x 64B linear).
__global__ __launch_bounds__(256, 8) void attn_kernel(const ushort_t* __restrict__ qg,
                                                      const ushort_t* __restrict__ kg,
                                                      const ushort_t* __restrict__ vtg,
                                                      ushort_t* __restrict__ yg) {
  __shared__ __align__(16) unsigned char lds[20480];
  const int n = blockIdx.x;                 // 0..2047
  const int xcd = n & 7, loc = n >> 3;      // XCD-grouped decode
  const int bh = xcd * 8 + (loc >> 5);      // 8 bh per XCD
  const int qi = loc & 31;                  // 0..31
  const int qt = (qi & 1) ? (qi >> 1) : 31 - (qi >> 1);  // long/short interleave
  const int tid = threadIdx.x;
  const int lane = tid & 63, w = tid >> 6;
  const int ln = lane & 15, gq = lane >> 4;

  const unsigned char* kbase = (const unsigned char*)kg + (size_t)bh * 2048 * 128;
  const unsigned char* vbase = (const unsigned char*)vtg + (size_t)bh * 64 * 4096;
  const ushort_t* qg_bh = qg + (size_t)bh * 2048 * 64;
  const unsigned pw = 16384 + w * 1024;

  const int q0 = qt * 64;
  const int nt2 = 2 * qt + 2;               // 32-kv tiles

  // stage 32-kv tile t: K 4KB (32 rows x 128B, swizzled), V 4KB (64 rows x 64B, linear)
  auto stage = [&](int buf, int t) {
    const unsigned char* kt = kbase + (size_t)t * 4096;
    const unsigned char* vt = vbase + t * 64;
    unsigned o = tid * 16;
    {
      unsigned r = o >> 7;
      unsigned c = (o & 127) ^ ((r & 7) << 4);
      gload16(kt + r * 128 + c, lds + buf * 4096 + o);
    }
    {
      unsigned r = o >> 6;
      unsigned c = o & 63;
      gload16(vt + (size_t)r * 4096 + c, lds + 8192 + buf * 4096 + o);
    }
  };

  // Q fragments: lane ln holds q-row (w*16+ln), k = st*32 + gq*8 + j
  const ushort_t* qrow = qg_bh + (size_t)(q0 + w * 16 + ln) * 64;
  short8 qa0 = *(const short8*)(qrow + gq * 8);
  short8 qa1 = *(const short8*)(qrow + 32 + gq * 8);

  f32x4 yacc[4] = {};
  float mrow = -3e38f, lrow = 0.f;   // lane-local state for q-row = w*16+ln
  const int qglob = q0 + w * 16 + ln;

  int cur = 0;
  stage(cur, 0);
  __syncthreads();

  for (int t = 0; t < nt2; ++t) {
    if (t + 1 < nt2) stage(cur ^ 1, t + 1);   // depth-1 prefetch (other buffer)
    const unsigned kb_ = cur * 4096;
    const unsigned vb_ = 8192 + cur * 4096;
    // swapped QK^T over 32 kv: S^T fragments; lane (gq,ln): q=ln, kv=f*16+gq*4+j
    f32x4 s[2];
    __builtin_amdgcn_s_setprio(1);
#pragma unroll
    for (int f = 0; f < 2; ++f) {
      unsigned row = f * 16 + ln;
      unsigned c0 = (gq * 16) ^ ((row & 7) << 4);
      short8 k0 = *(const short8*)(lds + kb_ + row * 128 + c0);
      short8 k1 = *(const short8*)(lds + kb_ + row * 128 + (c0 ^ 64));
      f32x4 z = {0.f, 0.f, 0.f, 0.f};
      z = mfma16(k0, qa0, z);
      s[f] = mfma16(k1, qa1, z);
    }
    __builtin_amdgcn_s_setprio(0);
    if (t >= nt2 - 2) {   // last two tiles overlap the diagonal: mask kv > q (global)
      const int kv0 = t * 32;
#pragma unroll
      for (int f = 0; f < 2; ++f) {
        int kvb = kv0 + f * 16 + gq * 4;
#pragma unroll
        for (int j = 0; j < 4; ++j)
          if (kvb + j > qglob) s[f][j] = -3e38f;
      }
    }
    // online softmax: lane holds 8 scores for q = w*16+ln
    // deferred rescale (THR=8 exp2-units) + fma-folded exp2
    {
      float rm = s[0][0];
#pragma unroll
      for (int f = 0; f < 2; ++f)
#pragma unroll
        for (int j = 0; j < 4; ++j) rm = fmaxf(rm, s[f][j]);
      rm = fmaxf(rm, __shfl_xor(rm, 16));
      rm = fmaxf(rm, __shfl_xor(rm, 32));
      if (__any((rm - mrow) * SC > 8.0f)) {
        float mnew = fmaxf(mrow, rm);
        float alpha = EXP2((mrow - mnew) * SC);
        lrow *= alpha;
        mrow = mnew;
#pragma unroll
        for (int j = 0; j < 4; ++j) {
          float aj = __shfl(alpha, gq * 4 + j);   // alpha of q-row gq*4+j
#pragma unroll
          for (int df = 0; df < 4; ++df) yacc[df][j] *= aj;
        }
      }
      float msc = mrow * SC;
      float rs = 0.f;
#pragma unroll
      for (int f = 0; f < 2; ++f)
#pragma unroll
        for (int j = 0; j < 4; ++j) {
          float p = EXP2(__builtin_fmaf(s[f][j], SC, -msc));
          s[f][j] = p;
          rs += p;
        }
      rs += __shfl_xor(rs, 16);
      rs += __shfl_xor(rs, 32);
      lrow += rs;
    }
    // write P -> per-wave LDS as P[16 q][32 kv] (64B rows, linear): lane owns row
    // q=ln, cols kv=f*16+gq*4..+3 -> one 8B write per f (2-way bank alias = free)
#pragma unroll
    for (int f = 0; f < 2; ++f) {
      us4 pk;
#pragma unroll
      for (int j = 0; j < 4; ++j) pk[j] = f2h(s[f][j]);
      *(us4*)(lds + pw + ln * 64 + f * 32 + gq * 8) = pk;
    }
    // PV: y[16 q][64 d] += P[16 q][32 kv] * V[32 kv][64 d]  (one k=32 MFMA per df)
    __builtin_amdgcn_s_setprio(1);
    {
      short8 pa = *(const short8*)(lds + pw + ln * 64 + gq * 16);
#pragma unroll
      for (int df = 0; df < 4; ++df) {
        short8 vb = *(const short8*)(lds + vb_ + (df * 16 + ln) * 64 + gq * 16);
        yacc[df] = mfma16(pa, vb, yacc[df]);
      }
    }
    __builtin_amdgcn_s_setprio(0);
    __syncthreads();   // drain prefetch + protect buffers
    cur ^= 1;
  }

  // epilogue: y[b][t][h*64+d] fp16 (lrow lives at lane q; broadcast)
#pragma unroll
  for (int j = 0; j < 4; ++j) {
    float lj = __shfl(lrow, gq * 4 + j);
    float rl = 1.0f / lj;
    int tq = q0 + w * 16 + gq * 4 + j;
#pragma unroll
    for (int df = 0; df < 4; ++df) {
      int col = (bh & 15) * 64 + df * 16 + ln;
      size_t off = ((size_t)(bh >> 4) * 2048 + tq) * 1024 + col;
      yg[off] = f2h(yacc[df][j] * rl);
    }
  }
}

extern "C" void kernel_launch(void* const* d_in, const int* in_sizes, int n_in,
                              void* d_out, int out_size, void* d_ws, size_t ws_size,
                              hipStream_t stream) {
  (void)in_sizes; (void)n_in; (void)out_size; (void)ws_size;
  const float* x     = (const float*)d_in[0];
  const float* wqkv  = (const float*)d_in[1];
  const float* wproj = (const float*)d_in[2];
  float* out = (float*)d_out;
  char* ws = (char*)d_ws;
  // ws layout (bytes)
  ushort_t* xb   = (ushort_t*)(ws);               // 16MB  (reused as y after QKV GEMM)
  ushort_t* wqkt = (ushort_t*)(ws + 16777216);    // 6MB
  ushort_t* wpt  = (ushort_t*)(ws + 23068672);    // 2MB
  ushort_t* qb_  = (ushort_t*)(ws + 25165824);    // 16MB [bh][t][d]
  ushort_t* kb_  = (ushort_t*)(ws + 41943040);    // 16MB [bh][t][d]
  ushort_t* vt   = (ushort_t*)(ws + 75497472);    // 16MB [bh][d][t] (written by gemm<0>)
  ushort_t* yb   = xb;

  cast_f32_f16<<<2048, 256, 0, stream>>>((const float4*)x, (us4*)xb, 2097152);
  tcast<<<dim3(96, 32), 256, 0, stream>>>(wqkv, wqkt, 1024, 3072);
  tcast<<<dim3(32, 32), 256, 0, stream>>>(wproj, wpt, 1024, 1024);
  gemm128<0><<<dim3(24, 64), 256, 0, stream>>>(xb, wqkt, 1024, 3072, qb_, kb_, vt, nullptr);
  attn_kernel<<<2048, 256, 0, stream>>>(qb_, kb_, vt, yb);
  gemm128<1><<<dim3(8, 64), 256, 0, stream>>>(yb, wpt, 1024, 1024, nullptr, nullptr, nullptr, out);
}

// Round 14
// 199.992 us; speedup vs baseline: 1.9779x; 1.3736x over previous
//
#include <hip/hip_runtime.h>
#include <stdint.h>

typedef unsigned short ushort_t;
typedef __attribute__((ext_vector_type(8))) short short8;
typedef __attribute__((ext_vector_type(8))) _Float16 half8;
typedef __attribute__((ext_vector_type(4))) float f32x4;
typedef __attribute__((ext_vector_type(4))) unsigned short us4;

#define AS1 __attribute__((address_space(1)))
#define AS3 __attribute__((address_space(3)))

#if __has_builtin(__builtin_amdgcn_exp2f)
#define EXP2(x) __builtin_amdgcn_exp2f(x)
#else
#define EXP2(x) exp2f(x)
#endif

// scores are multiplied by 8 (the reference's /scale bug); fold into exp2 base
#define SC 11.541560327111707f  // 8 * log2(e)

__device__ __forceinline__ ushort_t f2h(float f) {
  _Float16 h = (_Float16)f;   // v_cvt_f16_f32, RNE
  return __builtin_bit_cast(unsigned short, h);
}

__device__ __forceinline__ void gload16(const void* g, void* l) {
  __builtin_amdgcn_global_load_lds((AS1 const void*)g, (AS3 void*)l, 16, 0, 0);
}

__device__ __forceinline__ f32x4 mfma16(short8 a, short8 b, f32x4 c) {
  return __builtin_amdgcn_mfma_f32_16x16x32_f16(
      __builtin_bit_cast(half8, a), __builtin_bit_cast(half8, b), c, 0, 0, 0);
}

// ---------------- cast x fp32 -> fp16 ----------------
__global__ __launch_bounds__(256) void cast_f32_f16(const float4* __restrict__ in,
                                                    us4* __restrict__ out, int n4) {
  int i = blockIdx.x * 256 + threadIdx.x;
  int stride = gridDim.x * 256;
  for (; i < n4; i += stride) {
    float4 v = in[i];
    us4 o;
    o[0] = f2h(v.x); o[1] = f2h(v.y); o[2] = f2h(v.z); o[3] = f2h(v.w);
    out[i] = o;
  }
}

// ---------------- transpose-cast W [R][C] fp32 -> Wt [C][R] fp16 ----------------
__global__ __launch_bounds__(256) void tcast(const float* __restrict__ in,
                                             ushort_t* __restrict__ out, int R, int C) {
  __shared__ __align__(16) float lt[32][33];
  const int r0 = blockIdx.y * 32, c0 = blockIdx.x * 32;
  const int i = threadIdx.x;
  const int lr = i >> 3, lc = (i & 7) * 4;
  float4 v = *(const float4*)(in + (size_t)(r0 + lr) * C + c0 + lc);
  lt[lr][lc + 0] = v.x; lt[lr][lc + 1] = v.y; lt[lr][lc + 2] = v.z; lt[lr][lc + 3] = v.w;
  __syncthreads();
  const int oc = i >> 3;          // out row (a column c of in)
  const int orr = (i & 7) * 4;    // out col (row r of in)
  us4 o;
#pragma unroll
  for (int jj = 0; jj < 4; ++jj) o[jj] = f2h(lt[orr + jj][oc]);
  *(us4*)(out + (size_t)(c0 + oc) * R + r0 + orr) = o;
}

// ---------------- 128x128 fp16 GEMM, BK=64, A[M][K] x Bt[N][K] ----------------
// MODE 0: epilogue scatters Q,K into [bh][t][d] (fp16) and V TRANSPOSED into [bh][d][t]
// MODE 1: epilogue writes fp32 out[M][N]
template<int MODE>
__global__ __launch_bounds__(256) void gemm128(
    const ushort_t* __restrict__ A, const ushort_t* __restrict__ Bt, int K, int N,
    ushort_t* __restrict__ qo, ushort_t* __restrict__ ko, ushort_t* __restrict__ vo,
    float* __restrict__ outp)
{
  __shared__ __align__(16) unsigned char lds[32768];   // A tile 16K, B tile 16K
  const int tid = threadIdx.x;
  const int lane = tid & 63, w = tid >> 6;
  const int ln = lane & 15, gq = lane >> 4;
  const int wr = w >> 1, wc = w & 1;
  const int m0 = blockIdx.y * 128, n0 = blockIdx.x * 128;
  const size_t ldb = (size_t)K * 2;  // row bytes
  const unsigned char* ab = (const unsigned char*)A + (size_t)m0 * ldb;
  const unsigned char* bb = (const unsigned char*)Bt + (size_t)n0 * ldb;
  f32x4 acc[4][4] = {};
  const int nkt = K >> 6;
  for (int kb = 0; kb < nkt; ++kb) {
    const unsigned char* abk = ab + kb * 128;
    const unsigned char* bbk = bb + kb * 128;
#pragma unroll
    for (int e = 0; e < 4; ++e) {
      unsigned o = e * 4096 + tid * 16;
      unsigned r = o >> 7;
      unsigned c = (o & 127) ^ ((r & 7) << 4);   // pre-swizzled source
      gload16(abk + (size_t)r * ldb + c, lds + o);
      gload16(bbk + (size_t)r * ldb + c, lds + 16384 + o);
    }
    __syncthreads();
    short8 af[4][2], bf8[4][2];
#pragma unroll
    for (int mi = 0; mi < 4; ++mi) {
      unsigned row = wr * 64 + mi * 16 + ln;
      unsigned c0 = (gq * 16) ^ ((row & 7) << 4);
      af[mi][0] = *(const short8*)(lds + row * 128 + c0);
      af[mi][1] = *(const short8*)(lds + row * 128 + (c0 ^ 64));
    }
#pragma unroll
    for (int ni = 0; ni < 4; ++ni) {
      unsigned row = wc * 64 + ni * 16 + ln;
      unsigned c0 = (gq * 16) ^ ((row & 7) << 4);
      bf8[ni][0] = *(const short8*)(lds + 16384 + row * 128 + c0);
      bf8[ni][1] = *(const short8*)(lds + 16384 + row * 128 + (c0 ^ 64));
    }
#pragma unroll
    for (int mi = 0; mi < 4; ++mi)
#pragma unroll
      for (int ni = 0; ni < 4; ++ni) {
        acc[mi][ni] = mfma16(af[mi][0], bf8[ni][0], acc[mi][ni]);
        acc[mi][ni] = mfma16(af[mi][1], bf8[ni][1], acc[mi][ni]);
      }
    __syncthreads();
  }
  // epilogue: D layout col = lane&15, row = (lane>>4)*4 + j
  if (MODE == 0) {
#pragma unroll
    for (int mi = 0; mi < 4; ++mi)
#pragma unroll
      for (int ni = 0; ni < 4; ++ni) {
        int feat = n0 + wc * 64 + ni * 16 + ln;
        int sec = feat >> 10, cc = feat & 1023;   // sec is wave-uniform per (wc,ni)
        int hh = cc >> 6, dd = cc & 63;
        int tokbase = m0 + wr * 64 + mi * 16 + gq * 4;   // j=0 token (multiple of 4)
        int bh = (tokbase >> 11) * 16 + hh;
        int tloc = tokbase & 2047;
        if (sec == 2) {
          // V transposed: [bh][d][t], 4 consecutive tokens -> one 8B store
          us4 pk;
#pragma unroll
          for (int j = 0; j < 4; ++j) pk[j] = f2h(acc[mi][ni][j]);
          *(us4*)(vo + ((size_t)bh * 64 + dd) * 2048 + tloc) = pk;
        } else {
          ushort_t* dst = (sec == 0) ? qo : ko;
#pragma unroll
          for (int j = 0; j < 4; ++j) {
            size_t off = ((size_t)bh * 2048 + tloc + j) * 64 + dd;
            dst[off] = f2h(acc[mi][ni][j]);
          }
        }
      }
  } else {
#pragma unroll
    for (int mi = 0; mi < 4; ++mi)
#pragma unroll
      for (int ni = 0; ni < 4; ++ni)
#pragma unroll
        for (int j = 0; j < 4; ++j) {
          int token = m0 + wr * 64 + mi * 16 + gq * 4 + j;
          int feat  = n0 + wc * 64 + ni * 16 + ln;
          outp[(size_t)token * N + feat] = acc[mi][ni][j];
        }
  }
}

// ---------------- flash attention: merged-pair, QBLK=64, KVBLK=64 ----------------
// r11 structure (staged dbuf, depth-1 prefetch, 1 barrier/tile, 40960B LDS,
// 4 blocks/CU) but the pair's two q-tiles share each staged KV tile:
// compute B (qB=31-pair) every tile, A (qA=pair) while t<=qA. K fragments are
// ds_read once and feed both. Stages/block: 33 -> qB+1 (avg 24.5, -26%).
// Swapped QK^T softmax (lane-local), deferred rescale, fma-folded exp2, setprio.
// LDS: K dbuf @0/8192, Vt dbuf @16384/24576, P per-wave @32768 + w*2048.
__global__ __launch_bounds__(256) void attn_kernel(const ushort_t* __restrict__ qg,
                                                   const ushort_t* __restrict__ kg,
                                                   const ushort_t* __restrict__ vtg,
                                                   ushort_t* __restrict__ yg) {
  __shared__ __align__(16) unsigned char lds[40960];
  const int n = blockIdx.x;                 // 0..1023
  const int xcd = n & 7, loc = n >> 3;      // XCD-grouped decode
  const int bh = xcd * 8 + (loc >> 4);      // 0..63
  const int pr = loc & 15;
  const int pair = (pr & 1) ? (pr >> 1) : 15 - (pr >> 1);  // CU-local stage balance
  const int qA = pair, qB = 31 - pair;      // qB >= 16 > qA always
  const int q0A = qA * 64, q0B = qB * 64;
  const int nt = qB + 1;
  const int tid = threadIdx.x;
  const int lane = tid & 63, w = tid >> 6;
  const int ln = lane & 15, gq = lane >> 4;

  const unsigned char* kbase = (const unsigned char*)kg + (size_t)bh * 2048 * 128;
  const unsigned char* vbase = (const unsigned char*)vtg + (size_t)bh * 64 * 4096;
  const ushort_t* qg_bh = qg + (size_t)bh * 2048 * 64;
  const unsigned pw = 32768 + w * 2048;

  // stage kv tile t into buffer buf (K: 8KB contiguous; Vt: 64 rows x 128B, row stride 4KB)
  auto stage = [&](int buf, int t) {
    const unsigned char* kt = kbase + (size_t)t * 8192;
    const unsigned char* vt = vbase + t * 128;
#pragma unroll
    for (int e = 0; e < 2; ++e) {
      unsigned o = e * 4096 + tid * 16;
      unsigned r = o >> 7;
      unsigned c = (o & 127) ^ ((r & 7) << 4);
      gload16(kt + r * 128 + c, lds + buf * 8192 + o);
      gload16(vt + (size_t)r * 4096 + c, lds + 16384 + buf * 8192 + o);
    }
  };

  // Q fragments for both q-tiles: lane ln holds q-row (w*16+ln)
  const ushort_t* qrowA = qg_bh + (size_t)(q0A + w * 16 + ln) * 64;
  const ushort_t* qrowB = qg_bh + (size_t)(q0B + w * 16 + ln) * 64;
  short8 qaA0 = *(const short8*)(qrowA + gq * 8);
  short8 qaA1 = *(const short8*)(qrowA + 32 + gq * 8);
  short8 qaB0 = *(const short8*)(qrowB + gq * 8);
  short8 qaB1 = *(const short8*)(qrowB + 32 + gq * 8);

  f32x4 yaccA[4] = {}, yaccB[4] = {};
  float mrowA = -3e38f, lrowA = 0.f;
  float mrowB = -3e38f, lrowB = 0.f;

  int cur = 0;
  stage(cur, 0);
  __syncthreads();

  for (int t = 0; t < nt; ++t) {
    if (t + 1 < nt) stage(cur ^ 1, t + 1);   // depth-1 prefetch (other buffer)
    const unsigned kb_ = cur * 8192;
    const unsigned vb_ = 16384 + cur * 8192;
    const bool doA = (t <= qA);              // block-uniform

    // K fragments once per tile; QK^T for B always, for A while active
    f32x4 sA[4], sB[4];
    __builtin_amdgcn_s_setprio(1);
#pragma unroll
    for (int f = 0; f < 4; ++f) {
      unsigned row = f * 16 + ln;
      unsigned c0 = (gq * 16) ^ ((row & 7) << 4);
      short8 k0 = *(const short8*)(lds + kb_ + row * 128 + c0);
      short8 k1 = *(const short8*)(lds + kb_ + row * 128 + (c0 ^ 64));
      f32x4 zB = {0.f, 0.f, 0.f, 0.f};
      zB = mfma16(k0, qaB0, zB);
      sB[f] = mfma16(k1, qaB1, zB);
      if (doA) {
        f32x4 zA = {0.f, 0.f, 0.f, 0.f};
        zA = mfma16(k0, qaA0, zA);
        sA[f] = mfma16(k1, qaA1, zA);
      }
    }
    __builtin_amdgcn_s_setprio(0);

    // ---- A path (while active) ----
    if (doA) {
      if (t == qA) {   // diagonal for A: mask kv > q (local coords)
        int qloc = w * 16 + ln;
#pragma unroll
        for (int f = 0; f < 4; ++f) {
          int kvb = f * 16 + gq * 4;
#pragma unroll
          for (int j = 0; j < 4; ++j)
            if (kvb + j > qloc) sA[f][j] = -3e38f;
        }
      }
      {
        float rm = sA[0][0];
#pragma unroll
        for (int f = 0; f < 4; ++f)
#pragma unroll
          for (int j = 0; j < 4; ++j) rm = fmaxf(rm, sA[f][j]);
        rm = fmaxf(rm, __shfl_xor(rm, 16));
        rm = fmaxf(rm, __shfl_xor(rm, 32));
        if (__any((rm - mrowA) * SC > 8.0f)) {
          float mnew = fmaxf(mrowA, rm);
          float alpha = EXP2((mrowA - mnew) * SC);
          lrowA *= alpha;
          mrowA = mnew;
#pragma unroll
          for (int j = 0; j < 4; ++j) {
            float aj = __shfl(alpha, gq * 4 + j);
#pragma unroll
            for (int df = 0; df < 4; ++df) yaccA[df][j] *= aj;
          }
        }
        float msc = mrowA * SC;
        float rs = 0.f;
#pragma unroll
        for (int f = 0; f < 4; ++f)
#pragma unroll
          for (int j = 0; j < 4; ++j) {
            float p = EXP2(__builtin_fmaf(sA[f][j], SC, -msc));
            sA[f][j] = p;
            rs += p;
          }
        rs += __shfl_xor(rs, 16);
        rs += __shfl_xor(rs, 32);
        lrowA += rs;
      }
#pragma unroll
      for (int f = 0; f < 4; ++f) {
        us4 pk;
#pragma unroll
        for (int j = 0; j < 4; ++j) pk[j] = f2h(sA[f][j]);
        unsigned addr = (pw + ln * 128 + (f * 16 + gq * 4) * 2) ^ ((ln & 7) << 4);
        *(us4*)(lds + addr) = pk;
      }
      __builtin_amdgcn_s_setprio(1);
#pragma unroll
      for (int st = 0; st < 2; ++st) {
        unsigned pc = (st * 64 + gq * 16) ^ ((ln & 7) << 4);
        short8 pa = *(const short8*)(lds + pw + ln * 128 + pc);
#pragma unroll
        for (int df = 0; df < 4; ++df) {
          unsigned row = df * 16 + ln;
          unsigned c0 = (st * 64 + gq * 16) ^ ((row & 7) << 4);
          short8 vb = *(const short8*)(lds + vb_ + row * 128 + c0);
          yaccA[df] = mfma16(pa, vb, yaccA[df]);
        }
      }
      __builtin_amdgcn_s_setprio(0);
    }

    // ---- B path (always) ----
    {
      if (t == qB) {   // diagonal for B
        int qloc = w * 16 + ln;
#pragma unroll
        for (int f = 0; f < 4; ++f) {
          int kvb = f * 16 + gq * 4;
#pragma unroll
          for (int j = 0; j < 4; ++j)
            if (kvb + j > qloc) sB[f][j] = -3e38f;
        }
      }
      {
        float rm = sB[0][0];
#pragma unroll
        for (int f = 0; f < 4; ++f)
#pragma unroll
          for (int j = 0; j < 4; ++j) rm = fmaxf(rm, sB[f][j]);
        rm = fmaxf(rm, __shfl_xor(rm, 16));
        rm = fmaxf(rm, __shfl_xor(rm, 32));
        if (__any((rm - mrowB) * SC > 8.0f)) {
          float mnew = fmaxf(mrowB, rm);
          float alpha = EXP2((mrowB - mnew) * SC);
          lrowB *= alpha;
          mrowB = mnew;
#pragma unroll
          for (int j = 0; j < 4; ++j) {
            float aj = __shfl(alpha, gq * 4 + j);
#pragma unroll
            for (int df = 0; df < 4; ++df) yaccB[df][j] *= aj;
          }
        }
        float msc = mrowB * SC;
        float rs = 0.f;
#pragma unroll
        for (int f = 0; f < 4; ++f)
#pragma unroll
          for (int j = 0; j < 4; ++j) {
            float p = EXP2(__builtin_fmaf(sB[f][j], SC, -msc));
            sB[f][j] = p;
            rs += p;
          }
        rs += __shfl_xor(rs, 16);
        rs += __shfl_xor(rs, 32);
        lrowB += rs;
      }
#pragma unroll
      for (int f = 0; f < 4; ++f) {
        us4 pk;
#pragma unroll
        for (int j = 0; j < 4; ++j) pk[j] = f2h(sB[f][j]);
        unsigned addr = (pw + ln * 128 + (f * 16 + gq * 4) * 2) ^ ((ln & 7) << 4);
        *(us4*)(lds + addr) = pk;
      }
      __builtin_amdgcn_s_setprio(1);
#pragma unroll
      for (int st = 0; st < 2; ++st) {
        unsigned pc = (st * 64 + gq * 16) ^ ((ln & 7) << 4);
        short8 pa = *(const short8*)(lds + pw + ln * 128 + pc);
#pragma unroll
        for (int df = 0; df < 4; ++df) {
          unsigned row = df * 16 + ln;
          unsigned c0 = (st * 64 + gq * 16) ^ ((row & 7) << 4);
          short8 vb = *(const short8*)(lds + vb_ + row * 128 + c0);
          yaccB[df] = mfma16(pa, vb, yaccB[df]);
        }
      }
      __builtin_amdgcn_s_setprio(0);
    }

    __syncthreads();   // drain prefetch + protect buffers
    cur ^= 1;
  }

  // epilogue: both q-tiles, y[b][t][h*64+d] fp16 (lrow lives at lane q; broadcast)
#pragma unroll
  for (int j = 0; j < 4; ++j) {
    float ljA = __shfl(lrowA, gq * 4 + j);
    float ljB = __shfl(lrowB, gq * 4 + j);
    float rlA = 1.0f / ljA;
    float rlB = 1.0f / ljB;
    int tqA = q0A + w * 16 + gq * 4 + j;
    int tqB = q0B + w * 16 + gq * 4 + j;
#pragma unroll
    for (int df = 0; df < 4; ++df) {
      int col = (bh & 15) * 64 + df * 16 + ln;
      yg[((size_t)(bh >> 4) * 2048 + tqA) * 1024 + col] = f2h(yaccA[df][j] * rlA);
      yg[((size_t)(bh >> 4) * 2048 + tqB) * 1024 + col] = f2h(yaccB[df][j] * rlB);
    }
  }
}

extern "C" void kernel_launch(void* const* d_in, const int* in_sizes, int n_in,
                              void* d_out, int out_size, void* d_ws, size_t ws_size,
                              hipStream_t stream) {
  (void)in_sizes; (void)n_in; (void)out_size; (void)ws_size;
  const float* x     = (const float*)d_in[0];
  const float* wqkv  = (const float*)d_in[1];
  const float* wproj = (const float*)d_in[2];
  float* out = (float*)d_out;
  char* ws = (char*)d_ws;
  // ws layout (bytes)
  ushort_t* xb   = (ushort_t*)(ws);               // 16MB  (reused as y after QKV GEMM)
  ushort_t* wqkt = (ushort_t*)(ws + 16777216);    // 6MB
  ushort_t* wpt  = (ushort_t*)(ws + 23068672);    // 2MB
  ushort_t* qb_  = (ushort_t*)(ws + 25165824);    // 16MB [bh][t][d]
  ushort_t* kb_  = (ushort_t*)(ws + 41943040);    // 16MB [bh][t][d]
  ushort_t* vt   = (ushort_t*)(ws + 75497472);    // 16MB [bh][d][t] (written by gemm<0>)
  ushort_t* yb   = xb;

  cast_f32_f16<<<2048, 256, 0, stream>>>((const float4*)x, (us4*)xb, 2097152);
  tcast<<<dim3(96, 32), 256, 0, stream>>>(wqkv, wqkt, 1024, 3072);
  tcast<<<dim3(32, 32), 256, 0, stream>>>(wproj, wpt, 1024, 1024);
  gemm128<0><<<dim3(24, 64), 256, 0, stream>>>(xb, wqkt, 1024, 3072, qb_, kb_, vt, nullptr);
  attn_kernel<<<1024, 256, 0, stream>>>(qb_, kb_, vt, yb);
  gemm128<1><<<dim3(8, 64), 256, 0, stream>>>(yb, wpt, 1024, 1024, nullptr, nullptr, nullptr, out);
}

// Round 16
// 185.447 us; speedup vs baseline: 2.1330x; 1.0784x over previous
//
#include <hip/hip_runtime.h>
#include <stdint.h>

typedef unsigned short ushort_t;
typedef __attribute__((ext_vector_type(8))) short short8;
typedef __attribute__((ext_vector_type(8))) _Float16 half8;
typedef __attribute__((ext_vector_type(2))) __fp16 fp16x2;
typedef __attribute__((ext_vector_type(4))) float f32x4;
typedef __attribute__((ext_vector_type(4))) unsigned short us4;

#define AS1 __attribute__((address_space(1)))
#define AS3 __attribute__((address_space(3)))

#if __has_builtin(__builtin_amdgcn_exp2f)
#define EXP2(x) __builtin_amdgcn_exp2f(x)
#else
#define EXP2(x) exp2f(x)
#endif

// scores are multiplied by 8 (the reference's /scale bug); fold into exp2 base
#define SC 11.541560327111707f  // 8 * log2(e)

__device__ __forceinline__ ushort_t f2h(float f) {
  _Float16 h = (_Float16)f;   // v_cvt_f16_f32, RNE
  return __builtin_bit_cast(unsigned short, h);
}

// packed f32x4 -> 4 fp16 (8B) via v_cvt_pkrtz_f16_f32 (2 instrs instead of ~6)
__device__ __forceinline__ void packP(const f32x4& v, void* dst) {
#if __has_builtin(__builtin_amdgcn_cvt_pkrtz)
  fp16x2 a = __builtin_amdgcn_cvt_pkrtz(v[0], v[1]);
  fp16x2 b = __builtin_amdgcn_cvt_pkrtz(v[2], v[3]);
  uint2 w;
  w.x = __builtin_bit_cast(unsigned, a);
  w.y = __builtin_bit_cast(unsigned, b);
  *(uint2*)dst = w;
#else
  us4 pk;
#pragma unroll
  for (int j = 0; j < 4; ++j) pk[j] = f2h(v[j]);
  *(us4*)dst = pk;
#endif
}

__device__ __forceinline__ void gload16(const void* g, void* l) {
  __builtin_amdgcn_global_load_lds((AS1 const void*)g, (AS3 void*)l, 16, 0, 0);
}

__device__ __forceinline__ f32x4 mfma16(short8 a, short8 b, f32x4 c) {
  return __builtin_amdgcn_mfma_f32_16x16x32_f16(
      __builtin_bit_cast(half8, a), __builtin_bit_cast(half8, b), c, 0, 0, 0);
}

// ---------------- cast x fp32 -> fp16 ----------------
__global__ __launch_bounds__(256) void cast_f32_f16(const float4* __restrict__ in,
                                                    us4* __restrict__ out, int n4) {
  int i = blockIdx.x * 256 + threadIdx.x;
  int stride = gridDim.x * 256;
  for (; i < n4; i += stride) {
    float4 v = in[i];
    us4 o;
    o[0] = f2h(v.x); o[1] = f2h(v.y); o[2] = f2h(v.z); o[3] = f2h(v.w);
    out[i] = o;
  }
}

// ---------------- transpose-cast W [R][C] fp32 -> Wt [C][R] fp16 ----------------
__global__ __launch_bounds__(256) void tcast(const float* __restrict__ in,
                                             ushort_t* __restrict__ out, int R, int C) {
  __shared__ __align__(16) float lt[32][33];
  const int r0 = blockIdx.y * 32, c0 = blockIdx.x * 32;
  const int i = threadIdx.x;
  const int lr = i >> 3, lc = (i & 7) * 4;
  float4 v = *(const float4*)(in + (size_t)(r0 + lr) * C + c0 + lc);
  lt[lr][lc + 0] = v.x; lt[lr][lc + 1] = v.y; lt[lr][lc + 2] = v.z; lt[lr][lc + 3] = v.w;
  __syncthreads();
  const int oc = i >> 3;          // out row (a column c of in)
  const int orr = (i & 7) * 4;    // out col (row r of in)
  us4 o;
#pragma unroll
  for (int jj = 0; jj < 4; ++jj) o[jj] = f2h(lt[orr + jj][oc]);
  *(us4*)(out + (size_t)(c0 + oc) * R + r0 + orr) = o;
}

// ---------------- 128x128 fp16 GEMM, BK=64, A[M][K] x Bt[N][K] ----------------
// MODE 0: epilogue scatters Q,K into [bh][t][d] (fp16) and V TRANSPOSED into [bh][d][t]
// MODE 1: epilogue writes fp32 out[M][N]
template<int MODE>
__global__ __launch_bounds__(256) void gemm128(
    const ushort_t* __restrict__ A, const ushort_t* __restrict__ Bt, int K, int N,
    ushort_t* __restrict__ qo, ushort_t* __restrict__ ko, ushort_t* __restrict__ vo,
    float* __restrict__ outp)
{
  __shared__ __align__(16) unsigned char lds[32768];   // A tile 16K, B tile 16K
  const int tid = threadIdx.x;
  const int lane = tid & 63, w = tid >> 6;
  const int ln = lane & 15, gq = lane >> 4;
  const int wr = w >> 1, wc = w & 1;
  const int m0 = blockIdx.y * 128, n0 = blockIdx.x * 128;
  const size_t ldb = (size_t)K * 2;  // row bytes
  const unsigned char* ab = (const unsigned char*)A + (size_t)m0 * ldb;
  const unsigned char* bb = (const unsigned char*)Bt + (size_t)n0 * ldb;
  f32x4 acc[4][4] = {};
  const int nkt = K >> 6;
  for (int kb = 0; kb < nkt; ++kb) {
    const unsigned char* abk = ab + kb * 128;
    const unsigned char* bbk = bb + kb * 128;
#pragma unroll
    for (int e = 0; e < 4; ++e) {
      unsigned o = e * 4096 + tid * 16;
      unsigned r = o >> 7;
      unsigned c = (o & 127) ^ ((r & 7) << 4);   // pre-swizzled source
      gload16(abk + (size_t)r * ldb + c, lds + o);
      gload16(bbk + (size_t)r * ldb + c, lds + 16384 + o);
    }
    __syncthreads();
    short8 af[4][2], bf8[4][2];
#pragma unroll
    for (int mi = 0; mi < 4; ++mi) {
      unsigned row = wr * 64 + mi * 16 + ln;
      unsigned c0 = (gq * 16) ^ ((row & 7) << 4);
      af[mi][0] = *(const short8*)(lds + row * 128 + c0);
      af[mi][1] = *(const short8*)(lds + row * 128 + (c0 ^ 64));
    }
#pragma unroll
    for (int ni = 0; ni < 4; ++ni) {
      unsigned row = wc * 64 + ni * 16 + ln;
      unsigned c0 = (gq * 16) ^ ((row & 7) << 4);
      bf8[ni][0] = *(const short8*)(lds + 16384 + row * 128 + c0);
      bf8[ni][1] = *(const short8*)(lds + 16384 + row * 128 + (c0 ^ 64));
    }
#pragma unroll
    for (int mi = 0; mi < 4; ++mi)
#pragma unroll
      for (int ni = 0; ni < 4; ++ni) {
        acc[mi][ni] = mfma16(af[mi][0], bf8[ni][0], acc[mi][ni]);
        acc[mi][ni] = mfma16(af[mi][1], bf8[ni][1], acc[mi][ni]);
      }
    __syncthreads();
  }
  // epilogue: D layout col = lane&15, row = (lane>>4)*4 + j
  if (MODE == 0) {
#pragma unroll
    for (int mi = 0; mi < 4; ++mi)
#pragma unroll
      for (int ni = 0; ni < 4; ++ni) {
        int feat = n0 + wc * 64 + ni * 16 + ln;
        int sec = feat >> 10, cc = feat & 1023;   // sec is wave-uniform per (wc,ni)
        int hh = cc >> 6, dd = cc & 63;
        int tokbase = m0 + wr * 64 + mi * 16 + gq * 4;   // j=0 token (multiple of 4)
        int bh = (tokbase >> 11) * 16 + hh;
        int tloc = tokbase & 2047;
        if (sec == 2) {
          // V transposed: [bh][d][t], 4 consecutive tokens -> one 8B store
          us4 pk;
#pragma unroll
          for (int j = 0; j < 4; ++j) pk[j] = f2h(acc[mi][ni][j]);
          *(us4*)(vo + ((size_t)bh * 64 + dd) * 2048 + tloc) = pk;
        } else {
          ushort_t* dst = (sec == 0) ? qo : ko;
#pragma unroll
          for (int j = 0; j < 4; ++j) {
            size_t off = ((size_t)bh * 2048 + tloc + j) * 64 + dd;
            dst[off] = f2h(acc[mi][ni][j]);
          }
        }
      }
  } else {
#pragma unroll
    for (int mi = 0; mi < 4; ++mi)
#pragma unroll
      for (int ni = 0; ni < 4; ++ni)
#pragma unroll
        for (int j = 0; j < 4; ++j) {
          int token = m0 + wr * 64 + mi * 16 + gq * 4 + j;
          int feat  = n0 + wc * 64 + ni * 16 + ln;
          outp[(size_t)token * N + feat] = acc[mi][ni][j];
        }
  }
}

// ---------------- flash attention: causal pair-balanced, QBLK=64, KVBLK=64 ----------------
// r11-proven structure: sequential phases, staged dbuf, depth-1 prefetch, 1 barrier/tile,
// uniform 33 tiles/block (4 blocks/CU, single generation -> max==sum balance).
// Swapped QK^T (softmax lane-local, q = lane&15) + deferred rescale (THR=8 exp2-units)
// + fma-folded exp2 + setprio around MFMA clusters + pkrtz packed P-write.
// LDS: K dbuf @0/8192, Vt dbuf @16384/24576, P per-wave @32768 + w*2048 (40960B -> 4 blocks/CU)
__global__ __launch_bounds__(256) void attn_kernel(const ushort_t* __restrict__ qg,
                                                   const ushort_t* __restrict__ kg,
                                                   const ushort_t* __restrict__ vtg,
                                                   ushort_t* __restrict__ yg) {
  __shared__ __align__(16) unsigned char lds[40960];
  const int n = blockIdx.x;                 // 0..1023
  const int xcd = n & 7, loc = n >> 3;      // XCD-grouped decode
  const int bh = xcd * 8 + (loc >> 4);      // 0..63; all 16 pair-blocks of a bh on one XCD
  const int pair = loc & 15;                // 0..15
  const int tid = threadIdx.x;
  const int lane = tid & 63, w = tid >> 6;
  const int ln = lane & 15, gq = lane >> 4;

  const unsigned char* kbase = (const unsigned char*)kg + (size_t)bh * 2048 * 128;
  const unsigned char* vbase = (const unsigned char*)vtg + (size_t)bh * 64 * 4096;
  const ushort_t* qg_bh = qg + (size_t)bh * 2048 * 64;
  const unsigned pw = 32768 + w * 2048;

  // stage kv tile t into buffer buf (K: 8KB contiguous; Vt: 64 rows x 128B, row stride 4KB)
  auto stage = [&](int buf, int t) {
    const unsigned char* kt = kbase + (size_t)t * 8192;
    const unsigned char* vt = vbase + t * 128;
#pragma unroll
    for (int e = 0; e < 2; ++e) {
      unsigned o = e * 4096 + tid * 16;
      unsigned r = o >> 7;
      unsigned c = (o & 127) ^ ((r & 7) << 4);
      gload16(kt + r * 128 + c, lds + buf * 8192 + o);
      gload16(vt + (size_t)r * 4096 + c, lds + 16384 + buf * 8192 + o);
    }
  };

  int cur = 0;
  for (int ph = 0; ph < 2; ++ph) {
    const int qt = (ph == 0) ? pair : 31 - pair;
    const int q0 = qt * 64;
    const int nt = qt + 1;

    // Q fragments: lane ln holds q-row (w*16+ln), k = st*32 + gq*8 + j
    const ushort_t* qrow = qg_bh + (size_t)(q0 + w * 16 + ln) * 64;
    short8 qa0 = *(const short8*)(qrow + gq * 8);
    short8 qa1 = *(const short8*)(qrow + 32 + gq * 8);

    f32x4 yacc[4] = {};
    float mrow = -3e38f, lrow = 0.f;   // lane-local state for q-row = w*16+ln

    stage(cur, 0);
    __syncthreads();

    for (int t = 0; t < nt; ++t) {
      if (t + 1 < nt) stage(cur ^ 1, t + 1);   // depth-1 prefetch (other buffer)
      const unsigned kb_ = cur * 8192;
      const unsigned vb_ = 16384 + cur * 8192;
      // swapped QK^T: S^T[kv][q] fragments; col=ln=q, row=gq*4+j (+f*16 = kv)
      f32x4 s[4];
      __builtin_amdgcn_s_setprio(1);
#pragma unroll
      for (int f = 0; f < 4; ++f) {
        unsigned row = f * 16 + ln;
        unsigned c0 = (gq * 16) ^ ((row & 7) << 4);
        short8 k0 = *(const short8*)(lds + kb_ + row * 128 + c0);
        short8 k1 = *(const short8*)(lds + kb_ + row * 128 + (c0 ^ 64));
        f32x4 z = {0.f, 0.f, 0.f, 0.f};
        z = mfma16(k0, qa0, z);
        s[f] = mfma16(k1, qa1, z);
      }
      __builtin_amdgcn_s_setprio(0);
      if (t == nt - 1) {   // diagonal tile (kv0 == q0): mask kv > q in local coords
        int qloc = w * 16 + ln;
#pragma unroll
        for (int f = 0; f < 4; ++f) {
          int kvb = f * 16 + gq * 4;
#pragma unroll
          for (int j = 0; j < 4; ++j)
            if (kvb + j > qloc) s[f][j] = -3e38f;
        }
      }
      // online softmax: lane holds 16 scores all for q = w*16+ln
      // deferred rescale (THR=8 exp2-units) + fma-folded exp2
      {
        float rm = s[0][0];
#pragma unroll
        for (int f = 0; f < 4; ++f)
#pragma unroll
          for (int j = 0; j < 4; ++j) rm = fmaxf(rm, s[f][j]);
        rm = fmaxf(rm, __shfl_xor(rm, 16));
        rm = fmaxf(rm, __shfl_xor(rm, 32));
        if (__any((rm - mrow) * SC > 8.0f)) {
          float mnew = fmaxf(mrow, rm);
          float alpha = EXP2((mrow - mnew) * SC);
          lrow *= alpha;
          mrow = mnew;
#pragma unroll
          for (int j = 0; j < 4; ++j) {
            float aj = __shfl(alpha, gq * 4 + j);   // alpha of q-row gq*4+j
#pragma unroll
            for (int df = 0; df < 4; ++df) yacc[df][j] *= aj;
          }
        }
        float msc = mrow * SC;
        float rs = 0.f;
#pragma unroll
        for (int f = 0; f < 4; ++f)
#pragma unroll
          for (int j = 0; j < 4; ++j) {
            float p = EXP2(__builtin_fmaf(s[f][j], SC, -msc));
            s[f][j] = p;
            rs += p;
          }
        rs += __shfl_xor(rs, 16);
        rs += __shfl_xor(rs, 32);
        lrow += rs;
      }
      // write P -> LDS as P[16 q][64 kv]: lane owns row q=ln, cols kv=f*16+gq*4..+3
      // pkrtz packed conversion: 2 instrs per 8B write
#pragma unroll
      for (int f = 0; f < 4; ++f) {
        unsigned addr = (pw + ln * 128 + (f * 16 + gq * 4) * 2) ^ ((ln & 7) << 4);
        packP(s[f], lds + addr);
      }
      // PV: y[16 q][64 d] += P[16 q][64 kv] * V[64 kv][64 d]
      __builtin_amdgcn_s_setprio(1);
#pragma unroll
      for (int st = 0; st < 2; ++st) {
        unsigned pc = (st * 64 + gq * 16) ^ ((ln & 7) << 4);
        short8 pa = *(const short8*)(lds + pw + ln * 128 + pc);
#pragma unroll
        for (int df = 0; df < 4; ++df) {
          unsigned row = df * 16 + ln;
          unsigned c0 = (st * 64 + gq * 16) ^ ((row & 7) << 4);
          short8 vb = *(const short8*)(lds + vb_ + row * 128 + c0);
          yacc[df] = mfma16(pa, vb, yacc[df]);
        }
      }
      __builtin_amdgcn_s_setprio(0);
      __syncthreads();   // drain prefetch + protect buffers
      cur ^= 1;
    }

    // epilogue for this phase: y[b][t][h*64+d] fp16 (lrow lives at lane q; broadcast)
#pragma unroll
    for (int j = 0; j < 4; ++j) {
      float lj = __shfl(lrow, gq * 4 + j);
      float rl = 1.0f / lj;
      int tq = q0 + w * 16 + gq * 4 + j;
#pragma unroll
      for (int df = 0; df < 4; ++df) {
        int col = (bh & 15) * 64 + df * 16 + ln;
        size_t off = ((size_t)(bh >> 4) * 2048 + tq) * 1024 + col;
        yg[off] = f2h(yacc[df][j] * rl);
      }
    }
  }
}

extern "C" void kernel_launch(void* const* d_in, const int* in_sizes, int n_in,
                              void* d_out, int out_size, void* d_ws, size_t ws_size,
                              hipStream_t stream) {
  (void)in_sizes; (void)n_in; (void)out_size; (void)ws_size;
  const float* x     = (const float*)d_in[0];
  const float* wqkv  = (const float*)d_in[1];
  const float* wproj = (const float*)d_in[2];
  float* out = (float*)d_out;
  char* ws = (char*)d_ws;
  // ws layout (bytes)
  ushort_t* xb   = (ushort_t*)(ws);               // 16MB  (reused as y after QKV GEMM)
  ushort_t* wqkt = (ushort_t*)(ws + 16777216);    // 6MB
  ushort_t* wpt  = (ushort_t*)(ws + 23068672);    // 2MB
  ushort_t* qb_  = (ushort_t*)(ws + 25165824);    // 16MB [bh][t][d]
  ushort_t* kb_  = (ushort_t*)(ws + 41943040);    // 16MB [bh][t][d]
  ushort_t* vt   = (ushort_t*)(ws + 75497472);    // 16MB [bh][d][t] (written by gemm<0>)
  ushort_t* yb   = xb;

  cast_f32_f16<<<2048, 256, 0, stream>>>((const float4*)x, (us4*)xb, 2097152);
  tcast<<<dim3(96, 32), 256, 0, stream>>>(wqkv, wqkt, 1024, 3072);
  tcast<<<dim3(32, 32), 256, 0, stream>>>(wproj, wpt, 1024, 1024);
  gemm128<0><<<dim3(24, 64), 256, 0, stream>>>(xb, wqkt, 1024, 3072, qb_, kb_, vt, nullptr);
  attn_kernel<<<1024, 256, 0, stream>>>(qb_, kb_, vt, yb);
  gemm128<1><<<dim3(8, 64), 256, 0, stream>>>(yb, wpt, 1024, 1024, nullptr, nullptr, nullptr, out);
}

// Round 18
// 179.779 us; speedup vs baseline: 2.2002x; 1.0315x over previous
//
#include <hip/hip_runtime.h>
#include <stdint.h>

typedef unsigned short ushort_t;
typedef __attribute__((ext_vector_type(8))) short short8;
typedef __attribute__((ext_vector_type(8))) _Float16 half8;
typedef __attribute__((ext_vector_type(2))) __fp16 fp16x2;
typedef __attribute__((ext_vector_type(4))) float f32x4;
typedef __attribute__((ext_vector_type(4))) unsigned short us4;

#define AS1 __attribute__((address_space(1)))
#define AS3 __attribute__((address_space(3)))

#if __has_builtin(__builtin_amdgcn_exp2f)
#define EXP2(x) __builtin_amdgcn_exp2f(x)
#else
#define EXP2(x) exp2f(x)
#endif

// scores are multiplied by 8 (the reference's /scale bug); fold into exp2 base
#define SC 11.541560327111707f  // 8 * log2(e)

__device__ __forceinline__ ushort_t f2h(float f) {
  _Float16 h = (_Float16)f;   // v_cvt_f16_f32, RNE
  return __builtin_bit_cast(unsigned short, h);
}

// packed f32x4 -> 4 fp16 (8B) via v_cvt_pkrtz_f16_f32 (2 instrs instead of ~6)
__device__ __forceinline__ void packP(const f32x4& v, void* dst) {
#if __has_builtin(__builtin_amdgcn_cvt_pkrtz)
  fp16x2 a = __builtin_amdgcn_cvt_pkrtz(v[0], v[1]);
  fp16x2 b = __builtin_amdgcn_cvt_pkrtz(v[2], v[3]);
  uint2 w;
  w.x = __builtin_bit_cast(unsigned, a);
  w.y = __builtin_bit_cast(unsigned, b);
  *(uint2*)dst = w;
#else
  us4 pk;
#pragma unroll
  for (int j = 0; j < 4; ++j) pk[j] = f2h(v[j]);
  *(us4*)dst = pk;
#endif
}

__device__ __forceinline__ void gload16(const void* g, void* l) {
  __builtin_amdgcn_global_load_lds((AS1 const void*)g, (AS3 void*)l, 16, 0, 0);
}

__device__ __forceinline__ f32x4 mfma16(short8 a, short8 b, f32x4 c) {
  return __builtin_amdgcn_mfma_f32_16x16x32_f16(
      __builtin_bit_cast(half8, a), __builtin_bit_cast(half8, b), c, 0, 0, 0);
}

// ---------------- merged preprocessing: cast x + transpose-cast both weights ----------
// bid 0..2047: cast x fp32->fp16 (grid-stride over 2097152 float4)
// bid 2048..5119: tcast W_qkv [1024][3072] -> [3072][1024]
// bid 5120..6143: tcast W_proj [1024][1024] -> [1024][1024]
__global__ __launch_bounds__(256) void prep(const float4* __restrict__ x4,
                                            us4* __restrict__ xb4,
                                            const float* __restrict__ wqkv,
                                            ushort_t* __restrict__ wqkt,
                                            const float* __restrict__ wproj,
                                            ushort_t* __restrict__ wpt) {
  __shared__ __align__(16) float lt[32][33];
  const int bid = blockIdx.x;
  const int i = threadIdx.x;
  if (bid < 2048) {
    int idx = bid * 256 + i;
#pragma unroll 4
    for (; idx < 2097152; idx += 2048 * 256) {
      float4 v = x4[idx];
      us4 o;
      o[0] = f2h(v.x); o[1] = f2h(v.y); o[2] = f2h(v.z); o[3] = f2h(v.w);
      xb4[idx] = o;
    }
  } else {
    const float* in; ushort_t* out; int R, C, bx, by;
    if (bid < 5120) { int b = bid - 2048; in = wqkv; out = wqkt; R = 1024; C = 3072; bx = b % 96; by = b / 96; }
    else            { int b = bid - 5120; in = wproj; out = wpt;  R = 1024; C = 1024; bx = b % 32; by = b / 32; }
    const int r0 = by * 32, c0 = bx * 32;
    const int lr = i >> 3, lc = (i & 7) * 4;
    float4 v = *(const float4*)(in + (size_t)(r0 + lr) * C + c0 + lc);
    lt[lr][lc + 0] = v.x; lt[lr][lc + 1] = v.y; lt[lr][lc + 2] = v.z; lt[lr][lc + 3] = v.w;
    __syncthreads();
    const int oc = i >> 3;          // out row (a column c of in)
    const int orr = (i & 7) * 4;    // out col (row r of in)
    us4 o;
#pragma unroll
    for (int jj = 0; jj < 4; ++jj) o[jj] = f2h(lt[orr + jj][oc]);
    *(us4*)(out + (size_t)(c0 + oc) * R + r0 + orr) = o;
  }
}

// ---------------- 128x128 fp16 GEMM, BK=64, A[M][K] x Bt[N][K] ----------------
// MODE 0: epilogue scatters Q,K into [bh][t][d] (fp16) and V TRANSPOSED into [bh][d][t]
// MODE 1: epilogue writes fp32 out[M][N]
template<int MODE>
__global__ __launch_bounds__(256) void gemm128(
    const ushort_t* __restrict__ A, const ushort_t* __restrict__ Bt, int K, int N,
    ushort_t* __restrict__ qo, ushort_t* __restrict__ ko, ushort_t* __restrict__ vo,
    float* __restrict__ outp)
{
  __shared__ __align__(16) unsigned char lds[32768];   // A tile 16K, B tile 16K
  const int tid = threadIdx.x;
  const int lane = tid & 63, w = tid >> 6;
  const int ln = lane & 15, gq = lane >> 4;
  const int wr = w >> 1, wc = w & 1;
  const int m0 = blockIdx.y * 128, n0 = blockIdx.x * 128;
  const size_t ldb = (size_t)K * 2;  // row bytes
  const unsigned char* ab = (const unsigned char*)A + (size_t)m0 * ldb;
  const unsigned char* bb = (const unsigned char*)Bt + (size_t)n0 * ldb;
  f32x4 acc[4][4] = {};
  const int nkt = K >> 6;
  for (int kb = 0; kb < nkt; ++kb) {
    const unsigned char* abk = ab + kb * 128;
    const unsigned char* bbk = bb + kb * 128;
#pragma unroll
    for (int e = 0; e < 4; ++e) {
      unsigned o = e * 4096 + tid * 16;
      unsigned r = o >> 7;
      unsigned c = (o & 127) ^ ((r & 7) << 4);   // pre-swizzled source
      gload16(abk + (size_t)r * ldb + c, lds + o);
      gload16(bbk + (size_t)r * ldb + c, lds + 16384 + o);
    }
    __syncthreads();
    short8 af[4][2], bf8[4][2];
#pragma unroll
    for (int mi = 0; mi < 4; ++mi) {
      unsigned row = wr * 64 + mi * 16 + ln;
      unsigned c0 = (gq * 16) ^ ((row & 7) << 4);
      af[mi][0] = *(const short8*)(lds + row * 128 + c0);
      af[mi][1] = *(const short8*)(lds + row * 128 + (c0 ^ 64));
    }
#pragma unroll
    for (int ni = 0; ni < 4; ++ni) {
      unsigned row = wc * 64 + ni * 16 + ln;
      unsigned c0 = (gq * 16) ^ ((row & 7) << 4);
      bf8[ni][0] = *(const short8*)(lds + 16384 + row * 128 + c0);
      bf8[ni][1] = *(const short8*)(lds + 16384 + row * 128 + (c0 ^ 64));
    }
#pragma unroll
    for (int mi = 0; mi < 4; ++mi)
#pragma unroll
      for (int ni = 0; ni < 4; ++ni) {
        acc[mi][ni] = mfma16(af[mi][0], bf8[ni][0], acc[mi][ni]);
        acc[mi][ni] = mfma16(af[mi][1], bf8[ni][1], acc[mi][ni]);
      }
    __syncthreads();
  }
  // epilogue: D layout col = lane&15, row = (lane>>4)*4 + j
  if (MODE == 0) {
#pragma unroll
    for (int mi = 0; mi < 4; ++mi)
#pragma unroll
      for (int ni = 0; ni < 4; ++ni) {
        int feat = n0 + wc * 64 + ni * 16 + ln;
        int sec = feat >> 10, cc = feat & 1023;   // sec is wave-uniform per (wc,ni)
        int hh = cc >> 6, dd = cc & 63;
        int tokbase = m0 + wr * 64 + mi * 16 + gq * 4;   // j=0 token (multiple of 4)
        int bh = (tokbase >> 11) * 16 + hh;
        int tloc = tokbase & 2047;
        if (sec == 2) {
          // V transposed: [bh][d][t], 4 consecutive tokens -> one 8B store
          us4 pk;
#pragma unroll
          for (int j = 0; j < 4; ++j) pk[j] = f2h(acc[mi][ni][j]);
          *(us4*)(vo + ((size_t)bh * 64 + dd) * 2048 + tloc) = pk;
        } else {
          ushort_t* dst = (sec == 0) ? qo : ko;
#pragma unroll
          for (int j = 0; j < 4; ++j) {
            size_t off = ((size_t)bh * 2048 + tloc + j) * 64 + dd;
            dst[off] = f2h(acc[mi][ni][j]);
          }
        }
      }
  } else {
#pragma unroll
    for (int mi = 0; mi < 4; ++mi)
#pragma unroll
      for (int ni = 0; ni < 4; ++ni)
#pragma unroll
        for (int j = 0; j < 4; ++j) {
          int token = m0 + wr * 64 + mi * 16 + gq * 4 + j;
          int feat  = n0 + wc * 64 + ni * 16 + ln;
          outp[(size_t)token * N + feat] = acc[mi][ni][j];
        }
  }
}

// ---------------- flash attention: causal pair-balanced, QBLK=64, KVBLK=64 ----------------
// r11-proven structure: sequential phases, staged dbuf, depth-1 prefetch, 1 barrier/tile,
// uniform 33 tiles/block (4 blocks/CU, single generation -> max==sum balance).
// Swapped QK^T (softmax lane-local, q = lane&15) + deferred rescale (THR=8 exp2-units)
// + fma-folded exp2 + setprio around MFMA clusters + pkrtz packed P-write
// + deferred lrow column-reduce (once per phase instead of per tile).
// LDS: K dbuf @0/8192, Vt dbuf @16384/24576, P per-wave @32768 + w*2048 (40960B -> 4 blocks/CU)
__global__ __launch_bounds__(256) void attn_kernel(const ushort_t* __restrict__ qg,
                                                   const ushort_t* __restrict__ kg,
                                                   const ushort_t* __restrict__ vtg,
                                                   ushort_t* __restrict__ yg) {
  __shared__ __align__(16) unsigned char lds[40960];
  const int n = blockIdx.x;                 // 0..1023
  const int xcd = n & 7, loc = n >> 3;      // XCD-grouped decode
  const int bh = xcd * 8 + (loc >> 4);      // 0..63; all 16 pair-blocks of a bh on one XCD
  const int pair = loc & 15;                // 0..15
  const int tid = threadIdx.x;
  const int lane = tid & 63, w = tid >> 6;
  const int ln = lane & 15, gq = lane >> 4;

  const unsigned char* kbase = (const unsigned char*)kg + (size_t)bh * 2048 * 128;
  const unsigned char* vbase = (const unsigned char*)vtg + (size_t)bh * 64 * 4096;
  const ushort_t* qg_bh = qg + (size_t)bh * 2048 * 64;
  const unsigned pw = 32768 + w * 2048;

  // stage kv tile t into buffer buf (K: 8KB contiguous; Vt: 64 rows x 128B, row stride 4KB)
  auto stage = [&](int buf, int t) {
    const unsigned char* kt = kbase + (size_t)t * 8192;
    const unsigned char* vt = vbase + t * 128;
#pragma unroll
    for (int e = 0; e < 2; ++e) {
      unsigned o = e * 4096 + tid * 16;
      unsigned r = o >> 7;
      unsigned c = (o & 127) ^ ((r & 7) << 4);
      gload16(kt + r * 128 + c, lds + buf * 8192 + o);
      gload16(vt + (size_t)r * 4096 + c, lds + 16384 + buf * 8192 + o);
    }
  };

  int cur = 0;
  for (int ph = 0; ph < 2; ++ph) {
    const int qt = (ph == 0) ? pair : 31 - pair;
    const int q0 = qt * 64;
    const int nt = qt + 1;

    // Q fragments: lane ln holds q-row (w*16+ln), k = st*32 + gq*8 + j
    const ushort_t* qrow = qg_bh + (size_t)(q0 + w * 16 + ln) * 64;
    short8 qa0 = *(const short8*)(qrow + gq * 8);
    short8 qa1 = *(const short8*)(qrow + 32 + gq * 8);

    f32x4 yacc[4] = {};
    float mrow = -3e38f, lrow = 0.f;   // mrow column-uniform; lrow LANE-PARTIAL (reduced per phase)

    stage(cur, 0);
    __syncthreads();

    for (int t = 0; t < nt; ++t) {
      if (t + 1 < nt) stage(cur ^ 1, t + 1);   // depth-1 prefetch (other buffer)
      const unsigned kb_ = cur * 8192;
      const unsigned vb_ = 16384 + cur * 8192;
      // swapped QK^T: S^T[kv][q] fragments; col=ln=q, row=gq*4+j (+f*16 = kv)
      f32x4 s[4];
      __builtin_amdgcn_s_setprio(1);
#pragma unroll
      for (int f = 0; f < 4; ++f) {
        unsigned row = f * 16 + ln;
        unsigned c0 = (gq * 16) ^ ((row & 7) << 4);
        short8 k0 = *(const short8*)(lds + kb_ + row * 128 + c0);
        short8 k1 = *(const short8*)(lds + kb_ + row * 128 + (c0 ^ 64));
        f32x4 z = {0.f, 0.f, 0.f, 0.f};
        z = mfma16(k0, qa0, z);
        s[f] = mfma16(k1, qa1, z);
      }
      __builtin_amdgcn_s_setprio(0);
      if (t == nt - 1) {   // diagonal tile (kv0 == q0): mask kv > q in local coords
        int qloc = w * 16 + ln;
#pragma unroll
        for (int f = 0; f < 4; ++f) {
          int kvb = f * 16 + gq * 4;
#pragma unroll
          for (int j = 0; j < 4; ++j)
            if (kvb + j > qloc) s[f][j] = -3e38f;
        }
      }
      // online softmax: lane holds 16 scores all for q = w*16+ln
      // deferred rescale (THR=8 exp2-units) + fma-folded exp2 + deferred lrow reduce
      {
        float rm = s[0][0];
#pragma unroll
        for (int f = 0; f < 4; ++f)
#pragma unroll
          for (int j = 0; j < 4; ++j) rm = fmaxf(rm, s[f][j]);
        rm = fmaxf(rm, __shfl_xor(rm, 16));
        rm = fmaxf(rm, __shfl_xor(rm, 32));
        if (__any((rm - mrow) * SC > 8.0f)) {
          float mnew = fmaxf(mrow, rm);
          float alpha = EXP2((mrow - mnew) * SC);   // column-uniform
          lrow *= alpha;
          mrow = mnew;
#pragma unroll
          for (int j = 0; j < 4; ++j) {
            float aj = __shfl(alpha, gq * 4 + j);   // alpha of q-row gq*4+j
#pragma unroll
            for (int df = 0; df < 4; ++df) yacc[df][j] *= aj;
          }
        }
        float msc = mrow * SC;
        float rs = 0.f;
#pragma unroll
        for (int f = 0; f < 4; ++f)
#pragma unroll
          for (int j = 0; j < 4; ++j) {
            float p = EXP2(__builtin_fmaf(s[f][j], SC, -msc));
            s[f][j] = p;
            rs += p;
          }
        lrow += rs;   // lane-partial; column-reduced once per phase
      }
      // write P -> LDS as P[16 q][64 kv]: lane owns row q=ln, cols kv=f*16+gq*4..+3
      // pkrtz packed conversion: 2 instrs per 8B write
#pragma unroll
      for (int f = 0; f < 4; ++f) {
        unsigned addr = (pw + ln * 128 + (f * 16 + gq * 4) * 2) ^ ((ln & 7) << 4);
        packP(s[f], lds + addr);
      }
      // PV: y[16 q][64 d] += P[16 q][64 kv] * V[64 kv][64 d]
      __builtin_amdgcn_s_setprio(1);
#pragma unroll
      for (int st = 0; st < 2; ++st) {
        unsigned pc = (st * 64 + gq * 16) ^ ((ln & 7) << 4);
        short8 pa = *(const short8*)(lds + pw + ln * 128 + pc);
#pragma unroll
        for (int df = 0; df < 4; ++df) {
          unsigned row = df * 16 + ln;
          unsigned c0 = (st * 64 + gq * 16) ^ ((row & 7) << 4);
          short8 vb = *(const short8*)(lds + vb_ + row * 128 + c0);
          yacc[df] = mfma16(pa, vb, yacc[df]);
        }
      }
      __builtin_amdgcn_s_setprio(0);
      __syncthreads();   // drain prefetch + protect buffers
      cur ^= 1;
    }

    // finish deferred lrow reduce (column sum), then epilogue
    lrow += __shfl_xor(lrow, 16);
    lrow += __shfl_xor(lrow, 32);
#pragma unroll
    for (int j = 0; j < 4; ++j) {
      float lj = __shfl(lrow, gq * 4 + j);
      float rl = 1.0f / lj;
      int tq = q0 + w * 16 + gq * 4 + j;
#pragma unroll
      for (int df = 0; df < 4; ++df) {
        int col = (bh & 15) * 64 + df * 16 + ln;
        size_t off = ((size_t)(bh >> 4) * 2048 + tq) * 1024 + col;
        yg[off] = f2h(yacc[df][j] * rl);
      }
    }
  }
}

extern "C" void kernel_launch(void* const* d_in, const int* in_sizes, int n_in,
                              void* d_out, int out_size, void* d_ws, size_t ws_size,
                              hipStream_t stream) {
  (void)in_sizes; (void)n_in; (void)out_size; (void)ws_size;
  const float* x     = (const float*)d_in[0];
  const float* wqkv  = (const float*)d_in[1];
  const float* wproj = (const float*)d_in[2];
  float* out = (float*)d_out;
  char* ws = (char*)d_ws;
  // ws layout (bytes)
  ushort_t* xb   = (ushort_t*)(ws);               // 16MB  (reused as y after QKV GEMM)
  ushort_t* wqkt = (ushort_t*)(ws + 16777216);    // 6MB
  ushort_t* wpt  = (ushort_t*)(ws + 23068672);    // 2MB
  ushort_t* qb_  = (ushort_t*)(ws + 25165824);    // 16MB [bh][t][d]
  ushort_t* kb_  = (ushort_t*)(ws + 41943040);    // 16MB [bh][t][d]
  ushort_t* vt   = (ushort_t*)(ws + 75497472);    // 16MB [bh][d][t] (written by gemm<0>)
  ushort_t* yb   = xb;

  prep<<<6144, 256, 0, stream>>>((const float4*)x, (us4*)xb, wqkv, wqkt, wproj, wpt);
  gemm128<0><<<dim3(24, 64), 256, 0, stream>>>(xb, wqkt, 1024, 3072, qb_, kb_, vt, nullptr);
  attn_kernel<<<1024, 256, 0, stream>>>(qb_, kb_, vt, yb);
  gemm128<1><<<dim3(8, 64), 256, 0, stream>>>(yb, wpt, 1024, 1024, nullptr, nullptr, nullptr, out);
}

// Round 20
// 160.708 us; speedup vs baseline: 2.4613x; 1.1187x over previous
//
#include <hip/hip_runtime.h>
#include <stdint.h>

typedef unsigned short ushort_t;
typedef __attribute__((ext_vector_type(8))) short short8;
typedef __attribute__((ext_vector_type(8))) _Float16 half8;
typedef __attribute__((ext_vector_type(2))) __fp16 fp16x2;
typedef __attribute__((ext_vector_type(4))) float f32x4;
typedef __attribute__((ext_vector_type(4))) unsigned short us4;

#define AS1 __attribute__((address_space(1)))
#define AS3 __attribute__((address_space(3)))

#if __has_builtin(__builtin_amdgcn_exp2f)
#define EXP2(x) __builtin_amdgcn_exp2f(x)
#else
#define EXP2(x) exp2f(x)
#endif

// scores are multiplied by 8 (the reference's /scale bug); fold into exp2 base
#define SC 11.541560327111707f  // 8 * log2(e)

__device__ __forceinline__ ushort_t f2h(float f) {
  _Float16 h = (_Float16)f;   // v_cvt_f16_f32, RNE
  return __builtin_bit_cast(unsigned short, h);
}

// packed f32x4 -> 4 fp16 (8B) via v_cvt_pkrtz_f16_f32 (2 instrs instead of ~6)
__device__ __forceinline__ void packP(const f32x4& v, void* dst) {
#if __has_builtin(__builtin_amdgcn_cvt_pkrtz)
  fp16x2 a = __builtin_amdgcn_cvt_pkrtz(v[0], v[1]);
  fp16x2 b = __builtin_amdgcn_cvt_pkrtz(v[2], v[3]);
  uint2 w;
  w.x = __builtin_bit_cast(unsigned, a);
  w.y = __builtin_bit_cast(unsigned, b);
  *(uint2*)dst = w;
#else
  us4 pk;
#pragma unroll
  for (int j = 0; j < 4; ++j) pk[j] = f2h(v[j]);
  *(us4*)dst = pk;
#endif
}

__device__ __forceinline__ void gload16(const void* g, void* l) {
  __builtin_amdgcn_global_load_lds((AS1 const void*)g, (AS3 void*)l, 16, 0, 0);
}

__device__ __forceinline__ f32x4 mfma16(short8 a, short8 b, f32x4 c) {
  return __builtin_amdgcn_mfma_f32_16x16x32_f16(
      __builtin_bit_cast(half8, a), __builtin_bit_cast(half8, b), c, 0, 0, 0);
}

// ---------------- merged preprocessing: cast x + transpose-cast both weights ----------
// bid 0..2047: cast x fp32->fp16 (grid-stride over 2097152 float4)
// bid 2048..5119: tcast W_qkv [1024][3072] -> [3072][1024]
// bid 5120..6143: tcast W_proj [1024][1024] -> [1024][1024]
__global__ __launch_bounds__(256) void prep(const float4* __restrict__ x4,
                                            us4* __restrict__ xb4,
                                            const float* __restrict__ wqkv,
                                            ushort_t* __restrict__ wqkt,
                                            const float* __restrict__ wproj,
                                            ushort_t* __restrict__ wpt) {
  __shared__ __align__(16) float lt[32][33];
  const int bid = blockIdx.x;
  const int i = threadIdx.x;
  if (bid < 2048) {
    int idx = bid * 256 + i;
#pragma unroll 4
    for (; idx < 2097152; idx += 2048 * 256) {
      float4 v = x4[idx];
      us4 o;
      o[0] = f2h(v.x); o[1] = f2h(v.y); o[2] = f2h(v.z); o[3] = f2h(v.w);
      xb4[idx] = o;
    }
  } else {
    const float* in; ushort_t* out; int R, C, bx, by;
    if (bid < 5120) { int b = bid - 2048; in = wqkv; out = wqkt; R = 1024; C = 3072; bx = b % 96; by = b / 96; }
    else            { int b = bid - 5120; in = wproj; out = wpt;  R = 1024; C = 1024; bx = b % 32; by = b / 32; }
    const int r0 = by * 32, c0 = bx * 32;
    const int lr = i >> 3, lc = (i & 7) * 4;
    float4 v = *(const float4*)(in + (size_t)(r0 + lr) * C + c0 + lc);
    lt[lr][lc + 0] = v.x; lt[lr][lc + 1] = v.y; lt[lr][lc + 2] = v.z; lt[lr][lc + 3] = v.w;
    __syncthreads();
    const int oc = i >> 3;          // out row (a column c of in)
    const int orr = (i & 7) * 4;    // out col (row r of in)
    us4 o;
#pragma unroll
    for (int jj = 0; jj < 4; ++jj) o[jj] = f2h(lt[orr + jj][oc]);
    *(us4*)(out + (size_t)(c0 + oc) * R + r0 + orr) = o;
  }
}

// ---------------- 128x128 fp16 GEMM, BK=64, A[M][K] x Bt[N][K] ----------------
// MODE 0: epilogue scatters Q,K into [bh][t][d] (fp16) and V TRANSPOSED into [bh][d][t]
// MODE 1: epilogue writes fp32 out[M][N]
template<int MODE>
__global__ __launch_bounds__(256) void gemm128(
    const ushort_t* __restrict__ A, const ushort_t* __restrict__ Bt, int K, int N,
    ushort_t* __restrict__ qo, ushort_t* __restrict__ ko, ushort_t* __restrict__ vo,
    float* __restrict__ outp)
{
  __shared__ __align__(16) unsigned char lds[32768];   // A tile 16K, B tile 16K
  const int tid = threadIdx.x;
  const int lane = tid & 63, w = tid >> 6;
  const int ln = lane & 15, gq = lane >> 4;
  const int wr = w >> 1, wc = w & 1;
  const int m0 = blockIdx.y * 128, n0 = blockIdx.x * 128;
  const size_t ldb = (size_t)K * 2;  // row bytes
  const unsigned char* ab = (const unsigned char*)A + (size_t)m0 * ldb;
  const unsigned char* bb = (const unsigned char*)Bt + (size_t)n0 * ldb;
  f32x4 acc[4][4] = {};
  const int nkt = K >> 6;
  for (int kb = 0; kb < nkt; ++kb) {
    const unsigned char* abk = ab + kb * 128;
    const unsigned char* bbk = bb + kb * 128;
#pragma unroll
    for (int e = 0; e < 4; ++e) {
      unsigned o = e * 4096 + tid * 16;
      unsigned r = o >> 7;
      unsigned c = (o & 127) ^ ((r & 7) << 4);   // pre-swizzled source
      gload16(abk + (size_t)r * ldb + c, lds + o);
      gload16(bbk + (size_t)r * ldb + c, lds + 16384 + o);
    }
    __syncthreads();
    short8 af[4][2], bf8[4][2];
#pragma unroll
    for (int mi = 0; mi < 4; ++mi) {
      unsigned row = wr * 64 + mi * 16 + ln;
      unsigned c0 = (gq * 16) ^ ((row & 7) << 4);
      af[mi][0] = *(const short8*)(lds + row * 128 + c0);
      af[mi][1] = *(const short8*)(lds + row * 128 + (c0 ^ 64));
    }
#pragma unroll
    for (int ni = 0; ni < 4; ++ni) {
      unsigned row = wc * 64 + ni * 16 + ln;
      unsigned c0 = (gq * 16) ^ ((row & 7) << 4);
      bf8[ni][0] = *(const short8*)(lds + 16384 + row * 128 + c0);
      bf8[ni][1] = *(const short8*)(lds + 16384 + row * 128 + (c0 ^ 64));
    }
#pragma unroll
    for (int mi = 0; mi < 4; ++mi)
#pragma unroll
      for (int ni = 0; ni < 4; ++ni) {
        acc[mi][ni] = mfma16(af[mi][0], bf8[ni][0], acc[mi][ni]);
        acc[mi][ni] = mfma16(af[mi][1], bf8[ni][1], acc[mi][ni]);
      }
    __syncthreads();
  }
  // epilogue: D layout col = lane&15, row = (lane>>4)*4 + j
  if (MODE == 0) {
#pragma unroll
    for (int mi = 0; mi < 4; ++mi)
#pragma unroll
      for (int ni = 0; ni < 4; ++ni) {
        int feat = n0 + wc * 64 + ni * 16 + ln;
        int sec = feat >> 10, cc = feat & 1023;   // sec is wave-uniform per (wc,ni)
        int hh = cc >> 6, dd = cc & 63;
        int tokbase = m0 + wr * 64 + mi * 16 + gq * 4;   // j=0 token (multiple of 4)
        int bh = (tokbase >> 11) * 16 + hh;
        int tloc = tokbase & 2047;
        if (sec == 2) {
          // V transposed: [bh][d][t], 4 consecutive tokens -> one 8B store
          us4 pk;
#pragma unroll
          for (int j = 0; j < 4; ++j) pk[j] = f2h(acc[mi][ni][j]);
          *(us4*)(vo + ((size_t)bh * 64 + dd) * 2048 + tloc) = pk;
        } else {
          ushort_t* dst = (sec == 0) ? qo : ko;
#pragma unroll
          for (int j = 0; j < 4; ++j) {
            size_t off = ((size_t)bh * 2048 + tloc + j) * 64 + dd;
            dst[off] = f2h(acc[mi][ni][j]);
          }
        }
      }
  } else {
#pragma unroll
    for (int mi = 0; mi < 4; ++mi)
#pragma unroll
      for (int ni = 0; ni < 4; ++ni)
#pragma unroll
        for (int j = 0; j < 4; ++j) {
          int token = m0 + wr * 64 + mi * 16 + gq * 4 + j;
          int feat  = n0 + wc * 64 + ni * 16 + ln;
          outp[(size_t)token * N + feat] = acc[mi][ni][j];
        }
  }
}

// ---------------- flash attention: 8-wave blocks, QBLK=128, KVBLK=64 ----------------
// Same per-wave code as the r18-proven kernel (16 q-rows/wave, swapped QK^T lane-local
// softmax, deferred rescale, fma-folded exp2, pkrtz P-write, deferred lrow reduce,
// setprio, staged dbuf + depth-1 prefetch + 1 barrier/tile) — but 8 waves share each
// staged K/V tile: staging & barriers per q-row HALVE. Pair (p, 15-p) of 128-row
// q-tiles = 34 tiles/block, constant -> 512 uniform blocks, 2/CU, one generation.
// Diagonal: skip compute iff (t==nt-1 && w<4); mask global coords for t>=nt-2.
// LDS: K dbuf @0/8192, Vt dbuf @16384/24576, P per-wave @32768 + w*2048 (49152B -> 3/CU cap)
__global__ __launch_bounds__(512) void attn_kernel(const ushort_t* __restrict__ qg,
                                                   const ushort_t* __restrict__ kg,
                                                   const ushort_t* __restrict__ vtg,
                                                   ushort_t* __restrict__ yg) {
  __shared__ __align__(16) unsigned char lds[49152];
  const int n = blockIdx.x;                 // 0..511
  const int xcd = n & 7, loc = n >> 3;      // XCD-grouped decode, loc 0..63
  const int bh = xcd * 8 + (loc >> 3);      // 0..63; 8 bh per XCD (L2-resident K/V)
  const int pr = loc & 7;                   // 0..7
  const int tid = threadIdx.x;
  const int lane = tid & 63, w = tid >> 6;  // w 0..7
  const int ln = lane & 15, gq = lane >> 4;

  const unsigned char* kbase = (const unsigned char*)kg + (size_t)bh * 2048 * 128;
  const unsigned char* vbase = (const unsigned char*)vtg + (size_t)bh * 64 * 4096;
  const ushort_t* qg_bh = qg + (size_t)bh * 2048 * 64;
  const unsigned pw = 32768 + w * 2048;

  // stage kv tile t into buffer buf; 512 threads x 16B covers each 8KB sub-tile
  // (K: 8KB contiguous; Vt: 64 rows x 128B, row stride 4KB)
  auto stage = [&](int buf, int t) {
    const unsigned char* kt = kbase + (size_t)t * 8192;
    const unsigned char* vt = vbase + t * 128;
    unsigned o = tid * 16;                  // 0..8176
    unsigned r = o >> 7;
    unsigned c = (o & 127) ^ ((r & 7) << 4);
    gload16(kt + r * 128 + c, lds + buf * 8192 + o);
    gload16(vt + (size_t)r * 4096 + c, lds + 16384 + buf * 8192 + o);
  };

  int cur = 0;
  for (int ph = 0; ph < 2; ++ph) {
    const int qt = (ph == 0) ? pr : 15 - pr;   // 128-row q-tile index
    const int q0 = qt * 128;
    const int nt = 2 * qt + 2;                 // kv tiles of 64
    const int qglob = q0 + w * 16 + ln;        // this lane's q-row

    // Q fragments: lane ln holds q-row qglob, k = st*32 + gq*8 + j
    const ushort_t* qrow = qg_bh + (size_t)qglob * 64;
    short8 qa0 = *(const short8*)(qrow + gq * 8);
    short8 qa1 = *(const short8*)(qrow + 32 + gq * 8);

    f32x4 yacc[4] = {};
    float mrow = -3e38f, lrow = 0.f;   // mrow column-uniform; lrow LANE-PARTIAL

    stage(cur, 0);
    __syncthreads();

    for (int t = 0; t < nt; ++t) {
      if (t + 1 < nt) stage(cur ^ 1, t + 1);   // depth-1 prefetch (other buffer)
      const unsigned kb_ = cur * 8192;
      const unsigned vb_ = 16384 + cur * 8192;
      // last kv-tile is entirely future for waves 0..3 -> skip compute (wave-uniform)
      const bool active = !(t == nt - 1 && w < 4);
      if (active) {
        // swapped QK^T: S^T[kv][q] fragments; col=ln=q, row=gq*4+j (+f*16 = kv)
        f32x4 s[4];
        __builtin_amdgcn_s_setprio(1);
#pragma unroll
        for (int f = 0; f < 4; ++f) {
          unsigned row = f * 16 + ln;
          unsigned c0 = (gq * 16) ^ ((row & 7) << 4);
          short8 k0 = *(const short8*)(lds + kb_ + row * 128 + c0);
          short8 k1 = *(const short8*)(lds + kb_ + row * 128 + (c0 ^ 64));
          f32x4 z = {0.f, 0.f, 0.f, 0.f};
          z = mfma16(k0, qa0, z);
          s[f] = mfma16(k1, qa1, z);
        }
        __builtin_amdgcn_s_setprio(0);
        if (t >= nt - 2) {   // diagonal region: mask kv > q (global coords)
#pragma unroll
          for (int f = 0; f < 4; ++f) {
            int kvb = t * 64 + f * 16 + gq * 4;
#pragma unroll
            for (int j = 0; j < 4; ++j)
              if (kvb + j > qglob) s[f][j] = -3e38f;
          }
        }
        // online softmax: lane holds 16 scores all for q = qglob
        // deferred rescale (THR=8 exp2-units) + fma-folded exp2 + deferred lrow reduce
        {
          float rm = s[0][0];
#pragma unroll
          for (int f = 0; f < 4; ++f)
#pragma unroll
            for (int j = 0; j < 4; ++j) rm = fmaxf(rm, s[f][j]);
          rm = fmaxf(rm, __shfl_xor(rm, 16));
          rm = fmaxf(rm, __shfl_xor(rm, 32));
          if (__any((rm - mrow) * SC > 8.0f)) {
            float mnew = fmaxf(mrow, rm);
            float alpha = EXP2((mrow - mnew) * SC);   // column-uniform
            lrow *= alpha;
            mrow = mnew;
#pragma unroll
            for (int j = 0; j < 4; ++j) {
              float aj = __shfl(alpha, gq * 4 + j);   // alpha of q-row gq*4+j
#pragma unroll
              for (int df = 0; df < 4; ++df) yacc[df][j] *= aj;
            }
          }
          float msc = mrow * SC;
          float rs = 0.f;
#pragma unroll
          for (int f = 0; f < 4; ++f)
#pragma unroll
            for (int j = 0; j < 4; ++j) {
              float p = EXP2(__builtin_fmaf(s[f][j], SC, -msc));
              s[f][j] = p;
              rs += p;
            }
          lrow += rs;   // lane-partial; column-reduced once per phase
        }
        // write P -> LDS as P[16 q][64 kv]: lane owns row q=ln, cols kv=f*16+gq*4..+3
#pragma unroll
        for (int f = 0; f < 4; ++f) {
          unsigned addr = (pw + ln * 128 + (f * 16 + gq * 4) * 2) ^ ((ln & 7) << 4);
          packP(s[f], lds + addr);
        }
        // PV: y[16 q][64 d] += P[16 q][64 kv] * V[64 kv][64 d]
        __builtin_amdgcn_s_setprio(1);
#pragma unroll
        for (int st = 0; st < 2; ++st) {
          unsigned pc = (st * 64 + gq * 16) ^ ((ln & 7) << 4);
          short8 pa = *(const short8*)(lds + pw + ln * 128 + pc);
#pragma unroll
          for (int df = 0; df < 4; ++df) {
            unsigned row = df * 16 + ln;
            unsigned c0 = (st * 64 + gq * 16) ^ ((row & 7) << 4);
            short8 vb = *(const short8*)(lds + vb_ + row * 128 + c0);
            yacc[df] = mfma16(pa, vb, yacc[df]);
          }
        }
        __builtin_amdgcn_s_setprio(0);
      }
      __syncthreads();   // drain prefetch + protect buffers
      cur ^= 1;
    }

    // finish deferred lrow reduce (column sum), then epilogue
    lrow += __shfl_xor(lrow, 16);
    lrow += __shfl_xor(lrow, 32);
#pragma unroll
    for (int j = 0; j < 4; ++j) {
      float lj = __shfl(lrow, gq * 4 + j);
      float rl = 1.0f / lj;
      int tq = q0 + w * 16 + gq * 4 + j;
#pragma unroll
      for (int df = 0; df < 4; ++df) {
        int col = (bh & 15) * 64 + df * 16 + ln;
        size_t off = ((size_t)(bh >> 4) * 2048 + tq) * 1024 + col;
        yg[off] = f2h(yacc[df][j] * rl);
      }
    }
  }
}

extern "C" void kernel_launch(void* const* d_in, const int* in_sizes, int n_in,
                              void* d_out, int out_size, void* d_ws, size_t ws_size,
                              hipStream_t stream) {
  (void)in_sizes; (void)n_in; (void)out_size; (void)ws_size;
  const float* x     = (const float*)d_in[0];
  const float* wqkv  = (const float*)d_in[1];
  const float* wproj = (const float*)d_in[2];
  float* out = (float*)d_out;
  char* ws = (char*)d_ws;
  // ws layout (bytes)
  ushort_t* xb   = (ushort_t*)(ws);               // 16MB  (reused as y after QKV GEMM)
  ushort_t* wqkt = (ushort_t*)(ws + 16777216);    // 6MB
  ushort_t* wpt  = (ushort_t*)(ws + 23068672);    // 2MB
  ushort_t* qb_  = (ushort_t*)(ws + 25165824);    // 16MB [bh][t][d]
  ushort_t* kb_  = (ushort_t*)(ws + 41943040);    // 16MB [bh][t][d]
  ushort_t* vt   = (ushort_t*)(ws + 75497472);    // 16MB [bh][d][t] (written by gemm<0>)
  ushort_t* yb   = xb;

  prep<<<6144, 256, 0, stream>>>((const float4*)x, (us4*)xb, wqkv, wqkt, wproj, wpt);
  gemm128<0><<<dim3(24, 64), 256, 0, stream>>>(xb, wqkt, 1024, 3072, qb_, kb_, vt, nullptr);
  attn_kernel<<<512, 512, 0, stream>>>(qb_, kb_, vt, yb);
  gemm128<1><<<dim3(8, 64), 256, 0, stream>>>(yb, wpt, 1024, 1024, nullptr, nullptr, nullptr, out);
}